// Round 1
// baseline (31911.154 us; speedup 1.0000x reference)
//
#include <hip/hip_runtime.h>
#include <math.h>

#define B_ 8
#define N_ 1024
#define D_ 768
#define H_ 12
#define Y_ 64
#define M_ 3072
#define STEPS_ 12
#define ALPHA_ 0.1f
#define BETA_ 0.125f
#define EPS_ 1e-5f

// ---------------------------------------------------------------------------
// LayerNorm: one block per row (B*N rows of D=768), 256 threads, 3 elems each
// ---------------------------------------------------------------------------
__global__ __launch_bounds__(256) void ln_kernel(const float* __restrict__ x,
    const float* __restrict__ gamma, const float* __restrict__ beta,
    float* __restrict__ g) {
  const int row = blockIdx.x;
  const int t = threadIdx.x;
  const float* xr = x + (size_t)row * D_;
  float v0 = xr[t], v1 = xr[t + 256], v2 = xr[t + 512];
  float s = v0 + v1 + v2;
  float sq = v0 * v0 + v1 * v1 + v2 * v2;
  #pragma unroll
  for (int off = 1; off < 64; off <<= 1) {
    s += __shfl_xor(s, off);
    sq += __shfl_xor(sq, off);
  }
  __shared__ float ss[4], ssq[4];
  const int wid = t >> 6;
  if ((t & 63) == 0) { ss[wid] = s; ssq[wid] = sq; }
  __syncthreads();
  s = ss[0] + ss[1] + ss[2] + ss[3];
  sq = ssq[0] + ssq[1] + ssq[2] + ssq[3];
  const float mu = s * (1.0f / D_);
  const float var = sq * (1.0f / D_) - mu * mu;
  const float r = rsqrtf(var + EPS_);
  float* gr = g + (size_t)row * D_;
  gr[t]       = gamma[t]       * (v0 - mu) * r + beta[t];
  gr[t + 256] = gamma[t + 256] * (v1 - mu) * r + beta[t + 256];
  gr[t + 512] = gamma[t + 512] * (v2 - mu) * r + beta[t + 512];
}

// ---------------------------------------------------------------------------
// Generic fp32 tiled GEMM: C[M,N] (op) A[M,K] * B
//   TRANSB=1: B is [N,K] row-major (C = A * B^T)   -- "NT"
//   TRANSB=0: B is [K,N] row-major (C = A * B)     -- "NN"
//   EPI: 0 = store, 1 = store relu, 2 = C += alpha*acc (read-modify-write)
// BM=BN=64, BK=16, 256 threads, 4x4 per thread. M,N multiples of 64; K of 16.
// ---------------------------------------------------------------------------
template <bool TRANSB, int EPI>
__global__ __launch_bounds__(256) void gemm64(const float* __restrict__ A,
    const float* __restrict__ Bm, float* __restrict__ C,
    int M, int N, int K, float alpha) {
  __shared__ float As[16][68];
  __shared__ float Bs[16][68];
  const int n0 = blockIdx.x * 64;
  const int m0 = blockIdx.y * 64;
  const int t = threadIdx.x;
  const int tx = t & 15, ty = t >> 4;
  const int lr = t >> 2;          // row (0..63) for A / NT-B loads
  const int lk = (t & 3) * 4;     // k quad
  float acc[4][4] = {};
  for (int k0 = 0; k0 < K; k0 += 16) {
    float4 av = *(const float4*)(A + (size_t)(m0 + lr) * K + k0 + lk);
    As[lk + 0][lr] = av.x; As[lk + 1][lr] = av.y;
    As[lk + 2][lr] = av.z; As[lk + 3][lr] = av.w;
    if (TRANSB) {
      float4 bv = *(const float4*)(Bm + (size_t)(n0 + lr) * K + k0 + lk);
      Bs[lk + 0][lr] = bv.x; Bs[lk + 1][lr] = bv.y;
      Bs[lk + 2][lr] = bv.z; Bs[lk + 3][lr] = bv.w;
    } else {
      float4 bv = *(const float4*)(Bm + (size_t)(k0 + (t >> 4)) * N + n0 + (t & 15) * 4);
      *(float4*)&Bs[t >> 4][(t & 15) * 4] = bv;
    }
    __syncthreads();
    #pragma unroll
    for (int kk = 0; kk < 16; ++kk) {
      const float4 a4 = *(const float4*)&As[kk][ty * 4];
      const float4 b4 = *(const float4*)&Bs[kk][tx * 4];
      const float ar[4] = {a4.x, a4.y, a4.z, a4.w};
      const float br[4] = {b4.x, b4.y, b4.z, b4.w};
      #pragma unroll
      for (int i = 0; i < 4; ++i)
        #pragma unroll
        for (int j = 0; j < 4; ++j)
          acc[i][j] = fmaf(ar[i], br[j], acc[i][j]);
    }
    __syncthreads();
  }
  const int cm = m0 + ty * 4;
  const int cn = n0 + tx * 4;
  #pragma unroll
  for (int i = 0; i < 4; ++i) {
    float* cp = C + (size_t)(cm + i) * N + cn;
    if (EPI == 0) {
      float4 v = {acc[i][0], acc[i][1], acc[i][2], acc[i][3]};
      *(float4*)cp = v;
    } else if (EPI == 1) {
      float4 v = {fmaxf(acc[i][0], 0.f), fmaxf(acc[i][1], 0.f),
                  fmaxf(acc[i][2], 0.f), fmaxf(acc[i][3], 0.f)};
      *(float4*)cp = v;
    } else {
      float4 old = *(const float4*)cp;
      old.x += alpha * acc[i][0]; old.y += alpha * acc[i][1];
      old.z += alpha * acc[i][2]; old.w += alpha * acc[i][3];
      *(float4*)cp = old;
    }
  }
}

// ---------------------------------------------------------------------------
// Attention pass 1 (flash): per (b,h, 64-query tile):
//   lse[b,h,n] = logsumexp_m(BETA * k_m . q_n)
//   Aq[b,n,h*64+y] = sum_m softmax_m(..) * k[m,y]
// q,k stored [B, N, H*Y].
// ---------------------------------------------------------------------------
__global__ __launch_bounds__(256) void attn_pass1(const float* __restrict__ q,
    const float* __restrict__ k, float* __restrict__ Aq, float* __restrict__ lse) {
  __shared__ float qs[64][65];
  __shared__ float ks[64][65];
  __shared__ float ps[64][65];
  const int n0 = blockIdx.x * 64;
  const int h = blockIdx.y;
  const int b = blockIdx.z;
  const int t = threadIdx.x;
  const int tx = t & 15, ty = t >> 4;
  {
    const int r = t >> 2, c4 = (t & 3) * 16;
    const float* src = q + ((size_t)(b * N_ + n0 + r)) * D_ + h * Y_ + c4;
    #pragma unroll
    for (int ii = 0; ii < 4; ++ii) {
      float4 v = *(const float4*)(src + ii * 4);
      qs[r][c4 + ii * 4 + 0] = v.x; qs[r][c4 + ii * 4 + 1] = v.y;
      qs[r][c4 + ii * 4 + 2] = v.z; qs[r][c4 + ii * 4 + 3] = v.w;
    }
  }
  float mmax[4] = {-1e30f, -1e30f, -1e30f, -1e30f};
  float lsum[4] = {0.f, 0.f, 0.f, 0.f};
  float acc[4][4] = {};
  for (int mc = 0; mc < N_; mc += 64) {
    __syncthreads();  // protect ks/ps from previous iteration
    {
      const int r = t >> 2, c4 = (t & 3) * 16;
      const float* src = k + ((size_t)(b * N_ + mc + r)) * D_ + h * Y_ + c4;
      #pragma unroll
      for (int ii = 0; ii < 4; ++ii) {
        float4 v = *(const float4*)(src + ii * 4);
        ks[r][c4 + ii * 4 + 0] = v.x; ks[r][c4 + ii * 4 + 1] = v.y;
        ks[r][c4 + ii * 4 + 2] = v.z; ks[r][c4 + ii * 4 + 3] = v.w;
      }
    }
    __syncthreads();
    float s[4][4] = {};
    for (int y = 0; y < 64; ++y) {
      float a[4], bb[4];
      #pragma unroll
      for (int i = 0; i < 4; ++i) a[i] = qs[ty * 4 + i][y];
      #pragma unroll
      for (int j = 0; j < 4; ++j) bb[j] = ks[tx * 4 + j][y];
      #pragma unroll
      for (int i = 0; i < 4; ++i)
        #pragma unroll
        for (int j = 0; j < 4; ++j)
          s[i][j] = fmaf(a[i], bb[j], s[i][j]);
    }
    #pragma unroll
    for (int i = 0; i < 4; ++i) {
      #pragma unroll
      for (int j = 0; j < 4; ++j) s[i][j] *= BETA_;
      float rm = fmaxf(fmaxf(s[i][0], s[i][1]), fmaxf(s[i][2], s[i][3]));
      #pragma unroll
      for (int o = 1; o < 16; o <<= 1) rm = fmaxf(rm, __shfl_xor(rm, o));
      const float nm = fmaxf(mmax[i], rm);
      const float sc = __expf(mmax[i] - nm);
      float rs = 0.f;
      #pragma unroll
      for (int j = 0; j < 4; ++j) { s[i][j] = __expf(s[i][j] - nm); rs += s[i][j]; }
      #pragma unroll
      for (int o = 1; o < 16; o <<= 1) rs += __shfl_xor(rs, o);
      lsum[i] = lsum[i] * sc + rs;
      mmax[i] = nm;
      #pragma unroll
      for (int j = 0; j < 4; ++j) acc[i][j] *= sc;
      ps[ty * 4 + i][tx * 4 + 0] = s[i][0];
      ps[ty * 4 + i][tx * 4 + 1] = s[i][1];
      ps[ty * 4 + i][tx * 4 + 2] = s[i][2];
      ps[ty * 4 + i][tx * 4 + 3] = s[i][3];
    }
    __syncthreads();
    for (int m = 0; m < 64; ++m) {
      float p[4], kv[4];
      #pragma unroll
      for (int i = 0; i < 4; ++i) p[i] = ps[ty * 4 + i][m];
      #pragma unroll
      for (int j = 0; j < 4; ++j) kv[j] = ks[m][tx * 4 + j];
      #pragma unroll
      for (int i = 0; i < 4; ++i)
        #pragma unroll
        for (int j = 0; j < 4; ++j)
          acc[i][j] = fmaf(p[i], kv[j], acc[i][j]);
    }
  }
  #pragma unroll
  for (int i = 0; i < 4; ++i) {
    const float inv = 1.0f / lsum[i];
    float4 v = {acc[i][0] * inv, acc[i][1] * inv, acc[i][2] * inv, acc[i][3] * inv};
    *(float4*)(Aq + ((size_t)(b * N_ + n0 + ty * 4 + i)) * D_ + h * Y_ + tx * 4) = v;
  }
  if (tx == 0) {
    #pragma unroll
    for (int i = 0; i < 4; ++i)
      lse[((size_t)b * H_ + h) * N_ + n0 + ty * 4 + i] = mmax[i] + __logf(lsum[i]);
  }
}

// ---------------------------------------------------------------------------
// Attention pass 2: per (b,h, 64-key tile):
//   Ak[b,m,h*64+y] = sum_n exp(BETA * k_m . q_n - lse[n]) * q[n,y]
// ---------------------------------------------------------------------------
__global__ __launch_bounds__(256) void attn_pass2(const float* __restrict__ q,
    const float* __restrict__ k, const float* __restrict__ lse,
    float* __restrict__ Ak) {
  __shared__ float ks[64][65];
  __shared__ float qs[64][65];
  __shared__ float wsld[64][65];
  const int m0 = blockIdx.x * 64;
  const int h = blockIdx.y;
  const int b = blockIdx.z;
  const int t = threadIdx.x;
  const int tx = t & 15, ty = t >> 4;
  {
    const int r = t >> 2, c4 = (t & 3) * 16;
    const float* src = k + ((size_t)(b * N_ + m0 + r)) * D_ + h * Y_ + c4;
    #pragma unroll
    for (int ii = 0; ii < 4; ++ii) {
      float4 v = *(const float4*)(src + ii * 4);
      ks[r][c4 + ii * 4 + 0] = v.x; ks[r][c4 + ii * 4 + 1] = v.y;
      ks[r][c4 + ii * 4 + 2] = v.z; ks[r][c4 + ii * 4 + 3] = v.w;
    }
  }
  float acc[4][4] = {};
  for (int nc = 0; nc < N_; nc += 64) {
    __syncthreads();  // protect qs/wsld from previous iteration
    {
      const int r = t >> 2, c4 = (t & 3) * 16;
      const float* src = q + ((size_t)(b * N_ + nc + r)) * D_ + h * Y_ + c4;
      #pragma unroll
      for (int ii = 0; ii < 4; ++ii) {
        float4 v = *(const float4*)(src + ii * 4);
        qs[r][c4 + ii * 4 + 0] = v.x; qs[r][c4 + ii * 4 + 1] = v.y;
        qs[r][c4 + ii * 4 + 2] = v.z; qs[r][c4 + ii * 4 + 3] = v.w;
      }
    }
    __syncthreads();
    float ls[4];
    #pragma unroll
    for (int j = 0; j < 4; ++j)
      ls[j] = lse[((size_t)b * H_ + h) * N_ + nc + tx * 4 + j];
    float s[4][4] = {};
    for (int y = 0; y < 64; ++y) {
      float a[4], bb[4];
      #pragma unroll
      for (int i = 0; i < 4; ++i) a[i] = ks[ty * 4 + i][y];
      #pragma unroll
      for (int j = 0; j < 4; ++j) bb[j] = qs[tx * 4 + j][y];
      #pragma unroll
      for (int i = 0; i < 4; ++i)
        #pragma unroll
        for (int j = 0; j < 4; ++j)
          s[i][j] = fmaf(a[i], bb[j], s[i][j]);
    }
    #pragma unroll
    for (int i = 0; i < 4; ++i)
      #pragma unroll
      for (int j = 0; j < 4; ++j)
        wsld[ty * 4 + i][tx * 4 + j] = __expf(s[i][j] * BETA_ - ls[j]);
    __syncthreads();
    for (int n = 0; n < 64; ++n) {
      float w[4], qv[4];
      #pragma unroll
      for (int i = 0; i < 4; ++i) w[i] = wsld[ty * 4 + i][n];
      #pragma unroll
      for (int j = 0; j < 4; ++j) qv[j] = qs[n][tx * 4 + j];
      #pragma unroll
      for (int i = 0; i < 4; ++i)
        #pragma unroll
        for (int j = 0; j < 4; ++j)
          acc[i][j] = fmaf(w[i], qv[j], acc[i][j]);
    }
  }
  #pragma unroll
  for (int i = 0; i < 4; ++i) {
    float4 v = {acc[i][0], acc[i][1], acc[i][2], acc[i][3]};
    *(float4*)(Ak + ((size_t)(b * N_ + m0 + ty * 4 + i)) * D_ + h * Y_ + tx * 4) = v;
  }
}

// ---------------------------------------------------------------------------
extern "C" void kernel_launch(void* const* d_in, const int* in_sizes, int n_in,
                              void* d_out, int out_size, void* d_ws, size_t ws_size,
                              hipStream_t stream) {
  const float* x0    = (const float*)d_in[0];
  const float* gamma = (const float*)d_in[1];
  const float* beta  = (const float*)d_in[2];
  const float* wq    = (const float*)d_in[3];
  const float* wk    = (const float*)d_in[4];
  const float* xi    = (const float*)d_in[5];
  float* x = (float*)d_out;

  const size_t SZ = (size_t)B_ * N_ * D_;          // 6291456
  float* ws  = (float*)d_ws;
  float* g   = ws;
  float* q   = g + SZ;
  float* kb  = q + SZ;
  float* Aq  = kb + SZ;
  float* Ak  = Aq + SZ;
  float* lse = Ak + SZ;
  float* hid = lse + (size_t)B_ * H_ * N_;

  // Adaptive hid chunk (rows, multiple of 64) based on remaining workspace
  const long base_floats = (long)(5 * SZ + (size_t)B_ * H_ * N_);
  long avail = (long)(ws_size / 4) - base_floats;
  int R = B_ * N_;
  if (avail < (long)R * M_) {
    long r = avail / M_;
    r = (r / 64) * 64;
    if (r < 64) r = 64;
    if (r > B_ * N_) r = B_ * N_;
    R = (int)r;
  }

  hipMemcpyAsync(x, x0, SZ * sizeof(float), hipMemcpyDeviceToDevice, stream);

  const int MN = B_ * N_;  // 8192
  for (int step = 0; step < STEPS_; ++step) {
    ln_kernel<<<MN, 256, 0, stream>>>(x, gamma, beta, g);
    // q = g @ Wq^T, k = g @ Wk^T   (NT: W is [H*Y, D] row-major)
    gemm64<true, 0><<<dim3(D_ / 64, MN / 64), 256, 0, stream>>>(g, wq, q, MN, D_, D_, 1.f);
    gemm64<true, 0><<<dim3(D_ / 64, MN / 64), 256, 0, stream>>>(g, wk, kb, MN, D_, D_, 1.f);
    // attention gradient pieces
    attn_pass1<<<dim3(N_ / 64, H_, B_), 256, 0, stream>>>(q, kb, Aq, lse);
    attn_pass2<<<dim3(N_ / 64, H_, B_), 256, 0, stream>>>(q, kb, lse, Ak);
    // Hopfield: x += ALPHA * relu(g @ xi^T) @ xi   (chunked over rows)
    for (int r0 = 0; r0 < MN; r0 += R) {
      const int rows = (MN - r0) < R ? (MN - r0) : R;
      gemm64<true, 1><<<dim3(M_ / 64, rows / 64), 256, 0, stream>>>(
          g + (size_t)r0 * D_, xi, hid, rows, M_, D_, 1.f);
      gemm64<false, 2><<<dim3(D_ / 64, rows / 64), 256, 0, stream>>>(
          hid, xi, x + (size_t)r0 * D_, rows, D_, M_, ALPHA_);
    }
    // x += ALPHA * (Aq @ Wq + Ak @ Wk)   (NN: W viewed as [H*Y, D] = [K,N])
    gemm64<false, 2><<<dim3(D_ / 64, MN / 64), 256, 0, stream>>>(Aq, wq, x, MN, D_, D_, ALPHA_);
    gemm64<false, 2><<<dim3(D_ / 64, MN / 64), 256, 0, stream>>>(Ak, wk, x, MN, D_, D_, ALPHA_);
  }
}

// Round 2
// 15612.575 us; speedup vs baseline: 2.0439x; 2.0439x over previous
//
#include <hip/hip_runtime.h>
#include <math.h>

#define B_ 8
#define N_ 1024
#define D_ 768
#define H_ 12
#define Y_ 64
#define M_ 3072
#define STEPS_ 12
#define ALPHA_ 0.1f
#define BETA_ 0.125f
#define EPS_ 1e-5f

typedef __attribute__((ext_vector_type(8))) short bf16x8;
typedef __attribute__((ext_vector_type(4))) float f32x4;

__device__ inline unsigned short f2bf(float f) {
  union { float f; unsigned int u; } v; v.f = f;
  unsigned int r = (v.u + 0x7fffu + ((v.u >> 16) & 1u)) >> 16;
  return (unsigned short)r;
}

__device__ inline void async_copy16(const void* g, void* l) {
  __builtin_amdgcn_global_load_lds(
      (const __attribute__((address_space(1))) unsigned int*)g,
      (__attribute__((address_space(3))) unsigned int*)l, 16, 0, 0);
}

// ---------------------------------------------------------------------------
// LayerNorm -> bf16 g. One block per row, 256 threads, 3 elems each.
// ---------------------------------------------------------------------------
__global__ __launch_bounds__(256) void ln_kernel(const float* __restrict__ x,
    const float* __restrict__ gamma, const float* __restrict__ beta,
    unsigned short* __restrict__ g) {
  const int row = blockIdx.x;
  const int t = threadIdx.x;
  const float* xr = x + (size_t)row * D_;
  float v0 = xr[t], v1 = xr[t + 256], v2 = xr[t + 512];
  float s = v0 + v1 + v2;
  float sq = v0 * v0 + v1 * v1 + v2 * v2;
  #pragma unroll
  for (int off = 1; off < 64; off <<= 1) {
    s += __shfl_xor(s, off);
    sq += __shfl_xor(sq, off);
  }
  __shared__ float ss[4], ssq[4];
  const int wid = t >> 6;
  if ((t & 63) == 0) { ss[wid] = s; ssq[wid] = sq; }
  __syncthreads();
  s = ss[0] + ss[1] + ss[2] + ss[3];
  sq = ssq[0] + ssq[1] + ssq[2] + ssq[3];
  const float mu = s * (1.0f / D_);
  const float var = sq * (1.0f / D_) - mu * mu;
  const float r = rsqrtf(var + EPS_);
  unsigned short* gr = g + (size_t)row * D_;
  gr[t]       = f2bf(gamma[t]       * (v0 - mu) * r + beta[t]);
  gr[t + 256] = f2bf(gamma[t + 256] * (v1 - mu) * r + beta[t + 256]);
  gr[t + 512] = f2bf(gamma[t + 512] * (v2 - mu) * r + beta[t + 512]);
}

// ---------------------------------------------------------------------------
// fp32 -> bf16 convert
// ---------------------------------------------------------------------------
__global__ __launch_bounds__(256) void cvt_bf16(const float* __restrict__ in,
    unsigned short* __restrict__ out, int n) {
  int i = blockIdx.x * 256 + threadIdx.x;
  if (i < n) out[i] = f2bf(in[i]);
}

// ---------------------------------------------------------------------------
// transpose + convert: in[R][C] f32 -> out[C][R] bf16
// ---------------------------------------------------------------------------
__global__ __launch_bounds__(256) void transpose_cvt(const float* __restrict__ in,
    unsigned short* __restrict__ out, int R, int C) {
  __shared__ float tile[32][33];
  const int c0 = blockIdx.x * 32, r0 = blockIdx.y * 32;
  const int tx = threadIdx.x & 31, ty = threadIdx.x >> 5;  // ty: 0..7
  #pragma unroll
  for (int i = 0; i < 32; i += 8)
    tile[ty + i][tx] = in[(size_t)(r0 + ty + i) * C + c0 + tx];
  __syncthreads();
  #pragma unroll
  for (int i = 0; i < 32; i += 8)
    out[(size_t)(c0 + ty + i) * R + r0 + tx] = f2bf(tile[tx][ty + i]);
}

// ---------------------------------------------------------------------------
// bf16 MFMA GEMM, NT only: C[M,N] = A[M,K] * B[N,K]^T
// 128x128 tile, BK=64, 4 waves, global_load_lds staging with pre-swizzled
// source + XOR slot swizzle (slot ^= row&7) -> conflict-free ds_read_b128.
// EPI: 0 = store f32, 1 = store relu bf16, 2 = C(f32) += alpha*acc
// M,N multiples of 128; K multiple of 64.
// ---------------------------------------------------------------------------
template <int EPI>
__global__ __launch_bounds__(256) void gemm_mfma(
    const unsigned short* __restrict__ A, const unsigned short* __restrict__ Bm,
    void* __restrict__ Cv, int M, int N, int K, float alpha) {
  __shared__ __align__(16) unsigned short As[128 * 64];
  __shared__ __align__(16) unsigned short Bs[128 * 64];
  const int t = threadIdx.x;
  const int n0 = blockIdx.x * 128;
  const int m0 = blockIdx.y * 128;
  const int w = t >> 6;
  const int l = t & 63;
  const int wr = (w >> 1) * 64;
  const int wc = (w & 1) * 64;

  f32x4 acc[4][4];
  #pragma unroll
  for (int m = 0; m < 4; ++m)
    #pragma unroll
    for (int n = 0; n < 4; ++n) {
      f32x4 z = {0.f, 0.f, 0.f, 0.f};
      acc[m][n] = z;
    }

  for (int kt = 0; kt < K; kt += 64) {
    #pragma unroll
    for (int i = 0; i < 4; ++i) {
      const int flat = i * 4096 + t * 16;      // byte offset in tile
      const int row = flat >> 7;               // /128 B per row
      const int sphys = (flat >> 4) & 7;
      const int slog = sphys ^ (row & 7);
      async_copy16(A + (size_t)(m0 + row) * K + kt + slog * 8,
                   (char*)As + flat);
      async_copy16(Bm + (size_t)(n0 + row) * K + kt + slog * 8,
                   (char*)Bs + flat);
    }
    __syncthreads();
    #pragma unroll
    for (int kk = 0; kk < 2; ++kk) {
      bf16x8 a[4], b[4];
      const int lr = l & 15;
      const int sl = kk * 4 + (l >> 4);        // logical 16B slot 0..7
      #pragma unroll
      for (int m = 0; m < 4; ++m) {
        const int row = wr + m * 16 + lr;
        a[m] = *(const bf16x8*)((const char*)As + row * 128 + ((sl ^ (row & 7)) << 4));
      }
      #pragma unroll
      for (int n = 0; n < 4; ++n) {
        const int row = wc + n * 16 + lr;
        b[n] = *(const bf16x8*)((const char*)Bs + row * 128 + ((sl ^ (row & 7)) << 4));
      }
      #pragma unroll
      for (int m = 0; m < 4; ++m)
        #pragma unroll
        for (int n = 0; n < 4; ++n)
          acc[m][n] = __builtin_amdgcn_mfma_f32_16x16x32_bf16(a[m], b[n], acc[m][n], 0, 0, 0);
    }
    __syncthreads();
  }

  const int cr = (l >> 4) * 4;
  const int cc = l & 15;
  #pragma unroll
  for (int m = 0; m < 4; ++m) {
    #pragma unroll
    for (int n = 0; n < 4; ++n) {
      const int col = n0 + wc + n * 16 + cc;
      #pragma unroll
      for (int j = 0; j < 4; ++j) {
        const int row = m0 + wr + m * 16 + cr + j;
        const float v = acc[m][n][j];
        if (EPI == 0) {
          ((float*)Cv)[(size_t)row * N + col] = v;
        } else if (EPI == 1) {
          ((unsigned short*)Cv)[(size_t)row * N + col] = f2bf(v > 0.f ? v : 0.f);
        } else {
          float* cp = (float*)Cv + (size_t)row * N + col;
          *cp += alpha * v;
        }
      }
    }
  }
}

// ---------------------------------------------------------------------------
// Attention pass 1 (flash, fp32 q/k): lse + Aq (bf16 out)
// ---------------------------------------------------------------------------
__global__ __launch_bounds__(256) void attn_pass1(const float* __restrict__ q,
    const float* __restrict__ k, unsigned short* __restrict__ Aq,
    float* __restrict__ lse) {
  __shared__ float qs[64][65];
  __shared__ float ks[64][65];
  __shared__ float ps[64][65];
  const int n0 = blockIdx.x * 64;
  const int h = blockIdx.y;
  const int b = blockIdx.z;
  const int t = threadIdx.x;
  const int tx = t & 15, ty = t >> 4;
  {
    const int r = t >> 2, c4 = (t & 3) * 16;
    const float* src = q + ((size_t)(b * N_ + n0 + r)) * D_ + h * Y_ + c4;
    #pragma unroll
    for (int ii = 0; ii < 4; ++ii) {
      float4 v = *(const float4*)(src + ii * 4);
      qs[r][c4 + ii * 4 + 0] = v.x; qs[r][c4 + ii * 4 + 1] = v.y;
      qs[r][c4 + ii * 4 + 2] = v.z; qs[r][c4 + ii * 4 + 3] = v.w;
    }
  }
  float mmax[4] = {-1e30f, -1e30f, -1e30f, -1e30f};
  float lsum[4] = {0.f, 0.f, 0.f, 0.f};
  float acc[4][4] = {};
  for (int mc = 0; mc < N_; mc += 64) {
    __syncthreads();
    {
      const int r = t >> 2, c4 = (t & 3) * 16;
      const float* src = k + ((size_t)(b * N_ + mc + r)) * D_ + h * Y_ + c4;
      #pragma unroll
      for (int ii = 0; ii < 4; ++ii) {
        float4 v = *(const float4*)(src + ii * 4);
        ks[r][c4 + ii * 4 + 0] = v.x; ks[r][c4 + ii * 4 + 1] = v.y;
        ks[r][c4 + ii * 4 + 2] = v.z; ks[r][c4 + ii * 4 + 3] = v.w;
      }
    }
    __syncthreads();
    float s[4][4] = {};
    for (int y = 0; y < 64; ++y) {
      float a[4], bb[4];
      #pragma unroll
      for (int i = 0; i < 4; ++i) a[i] = qs[ty * 4 + i][y];
      #pragma unroll
      for (int j = 0; j < 4; ++j) bb[j] = ks[tx * 4 + j][y];
      #pragma unroll
      for (int i = 0; i < 4; ++i)
        #pragma unroll
        for (int j = 0; j < 4; ++j)
          s[i][j] = fmaf(a[i], bb[j], s[i][j]);
    }
    #pragma unroll
    for (int i = 0; i < 4; ++i) {
      #pragma unroll
      for (int j = 0; j < 4; ++j) s[i][j] *= BETA_;
      float rm = fmaxf(fmaxf(s[i][0], s[i][1]), fmaxf(s[i][2], s[i][3]));
      #pragma unroll
      for (int o = 1; o < 16; o <<= 1) rm = fmaxf(rm, __shfl_xor(rm, o));
      const float nm = fmaxf(mmax[i], rm);
      const float sc = __expf(mmax[i] - nm);
      float rs = 0.f;
      #pragma unroll
      for (int j = 0; j < 4; ++j) { s[i][j] = __expf(s[i][j] - nm); rs += s[i][j]; }
      #pragma unroll
      for (int o = 1; o < 16; o <<= 1) rs += __shfl_xor(rs, o);
      lsum[i] = lsum[i] * sc + rs;
      mmax[i] = nm;
      #pragma unroll
      for (int j = 0; j < 4; ++j) acc[i][j] *= sc;
      ps[ty * 4 + i][tx * 4 + 0] = s[i][0];
      ps[ty * 4 + i][tx * 4 + 1] = s[i][1];
      ps[ty * 4 + i][tx * 4 + 2] = s[i][2];
      ps[ty * 4 + i][tx * 4 + 3] = s[i][3];
    }
    __syncthreads();
    for (int m = 0; m < 64; ++m) {
      float p[4], kv[4];
      #pragma unroll
      for (int i = 0; i < 4; ++i) p[i] = ps[ty * 4 + i][m];
      #pragma unroll
      for (int j = 0; j < 4; ++j) kv[j] = ks[m][tx * 4 + j];
      #pragma unroll
      for (int i = 0; i < 4; ++i)
        #pragma unroll
        for (int j = 0; j < 4; ++j)
          acc[i][j] = fmaf(p[i], kv[j], acc[i][j]);
    }
  }
  #pragma unroll
  for (int i = 0; i < 4; ++i) {
    const float inv = 1.0f / lsum[i];
    unsigned int lo = (unsigned int)f2bf(acc[i][0] * inv) | ((unsigned int)f2bf(acc[i][1] * inv) << 16);
    unsigned int hi = (unsigned int)f2bf(acc[i][2] * inv) | ((unsigned int)f2bf(acc[i][3] * inv) << 16);
    uint2 pk = {lo, hi};
    *(uint2*)(Aq + ((size_t)(b * N_ + n0 + ty * 4 + i)) * D_ + h * Y_ + tx * 4) = pk;
  }
  if (tx == 0) {
    #pragma unroll
    for (int i = 0; i < 4; ++i)
      lse[((size_t)b * H_ + h) * N_ + n0 + ty * 4 + i] = mmax[i] + __logf(lsum[i]);
  }
}

// ---------------------------------------------------------------------------
// Attention pass 2 (fp32 q/k): Ak (bf16 out)
// ---------------------------------------------------------------------------
__global__ __launch_bounds__(256) void attn_pass2(const float* __restrict__ q,
    const float* __restrict__ k, const float* __restrict__ lse,
    unsigned short* __restrict__ Ak) {
  __shared__ float ks[64][65];
  __shared__ float qs[64][65];
  __shared__ float wsld[64][65];
  const int m0 = blockIdx.x * 64;
  const int h = blockIdx.y;
  const int b = blockIdx.z;
  const int t = threadIdx.x;
  const int tx = t & 15, ty = t >> 4;
  {
    const int r = t >> 2, c4 = (t & 3) * 16;
    const float* src = k + ((size_t)(b * N_ + m0 + r)) * D_ + h * Y_ + c4;
    #pragma unroll
    for (int ii = 0; ii < 4; ++ii) {
      float4 v = *(const float4*)(src + ii * 4);
      ks[r][c4 + ii * 4 + 0] = v.x; ks[r][c4 + ii * 4 + 1] = v.y;
      ks[r][c4 + ii * 4 + 2] = v.z; ks[r][c4 + ii * 4 + 3] = v.w;
    }
  }
  float acc[4][4] = {};
  for (int nc = 0; nc < N_; nc += 64) {
    __syncthreads();
    {
      const int r = t >> 2, c4 = (t & 3) * 16;
      const float* src = q + ((size_t)(b * N_ + nc + r)) * D_ + h * Y_ + c4;
      #pragma unroll
      for (int ii = 0; ii < 4; ++ii) {
        float4 v = *(const float4*)(src + ii * 4);
        qs[r][c4 + ii * 4 + 0] = v.x; qs[r][c4 + ii * 4 + 1] = v.y;
        qs[r][c4 + ii * 4 + 2] = v.z; qs[r][c4 + ii * 4 + 3] = v.w;
      }
    }
    __syncthreads();
    float ls[4];
    #pragma unroll
    for (int j = 0; j < 4; ++j)
      ls[j] = lse[((size_t)b * H_ + h) * N_ + nc + tx * 4 + j];
    float s[4][4] = {};
    for (int y = 0; y < 64; ++y) {
      float a[4], bb[4];
      #pragma unroll
      for (int i = 0; i < 4; ++i) a[i] = ks[ty * 4 + i][y];
      #pragma unroll
      for (int j = 0; j < 4; ++j) bb[j] = qs[tx * 4 + j][y];
      #pragma unroll
      for (int i = 0; i < 4; ++i)
        #pragma unroll
        for (int j = 0; j < 4; ++j)
          s[i][j] = fmaf(a[i], bb[j], s[i][j]);
    }
    #pragma unroll
    for (int i = 0; i < 4; ++i)
      #pragma unroll
      for (int j = 0; j < 4; ++j)
        wsld[ty * 4 + i][tx * 4 + j] = __expf(s[i][j] * BETA_ - ls[j]);
    __syncthreads();
    for (int n = 0; n < 64; ++n) {
      float w[4], qv[4];
      #pragma unroll
      for (int i = 0; i < 4; ++i) w[i] = wsld[ty * 4 + i][n];
      #pragma unroll
      for (int j = 0; j < 4; ++j) qv[j] = qs[n][tx * 4 + j];
      #pragma unroll
      for (int i = 0; i < 4; ++i)
        #pragma unroll
        for (int j = 0; j < 4; ++j)
          acc[i][j] = fmaf(w[i], qv[j], acc[i][j]);
    }
  }
  #pragma unroll
  for (int i = 0; i < 4; ++i) {
    unsigned int lo = (unsigned int)f2bf(acc[i][0]) | ((unsigned int)f2bf(acc[i][1]) << 16);
    unsigned int hi = (unsigned int)f2bf(acc[i][2]) | ((unsigned int)f2bf(acc[i][3]) << 16);
    uint2 pk = {lo, hi};
    *(uint2*)(Ak + ((size_t)(b * N_ + m0 + ty * 4 + i)) * D_ + h * Y_ + tx * 4) = pk;
  }
}

// ---------------------------------------------------------------------------
extern "C" void kernel_launch(void* const* d_in, const int* in_sizes, int n_in,
                              void* d_out, int out_size, void* d_ws, size_t ws_size,
                              hipStream_t stream) {
  const float* x0    = (const float*)d_in[0];
  const float* gamma = (const float*)d_in[1];
  const float* beta  = (const float*)d_in[2];
  const float* wq    = (const float*)d_in[3];
  const float* wk    = (const float*)d_in[4];
  const float* xi    = (const float*)d_in[5];
  float* x = (float*)d_out;

  const size_t SZ = (size_t)B_ * N_ * D_;   // 6291456
  char* wsp = (char*)d_ws;
  size_t off = 0;
  auto alloc = [&](size_t bytes) -> void* {
    off = (off + 255) & ~(size_t)255;
    void* p = wsp + off;
    off += bytes;
    return p;
  };
  unsigned short* g_bf  = (unsigned short*)alloc(SZ * 2);
  float*          q     = (float*)alloc(SZ * 4);
  float*          kb    = (float*)alloc(SZ * 4);
  unsigned short* Aq_bf = (unsigned short*)alloc(SZ * 2);
  unsigned short* Ak_bf = (unsigned short*)alloc(SZ * 2);
  float*          lse   = (float*)alloc((size_t)B_ * H_ * N_ * 4);
  unsigned short* wq_bf  = (unsigned short*)alloc((size_t)D_ * D_ * 2);
  unsigned short* wk_bf  = (unsigned short*)alloc((size_t)D_ * D_ * 2);
  unsigned short* wqT_bf = (unsigned short*)alloc((size_t)D_ * D_ * 2);
  unsigned short* wkT_bf = (unsigned short*)alloc((size_t)D_ * D_ * 2);
  unsigned short* xi_bf  = (unsigned short*)alloc((size_t)M_ * D_ * 2);
  unsigned short* xiT_bf = (unsigned short*)alloc((size_t)M_ * D_ * 2);
  off = (off + 255) & ~(size_t)255;
  unsigned short* hid_bf = (unsigned short*)(wsp + off);
  size_t avail = ws_size > off ? ws_size - off : 0;
  long rmax = (long)(avail / ((size_t)M_ * 2));
  int R = (int)((rmax / 128) * 128);
  if (R > B_ * N_) R = B_ * N_;
  if (R < 128) R = 128;

  // One-time weight conversions/transposes
  const int WQN = D_ * D_;   // 589824
  const int XIN = M_ * D_;   // 2359296
  cvt_bf16<<<(WQN + 255) / 256, 256, 0, stream>>>(wq, wq_bf, WQN);
  cvt_bf16<<<(WQN + 255) / 256, 256, 0, stream>>>(wk, wk_bf, WQN);
  cvt_bf16<<<(XIN + 255) / 256, 256, 0, stream>>>(xi, xi_bf, XIN);
  transpose_cvt<<<dim3(D_ / 32, D_ / 32), 256, 0, stream>>>(wq, wqT_bf, D_, D_);
  transpose_cvt<<<dim3(D_ / 32, D_ / 32), 256, 0, stream>>>(wk, wkT_bf, D_, D_);
  transpose_cvt<<<dim3(D_ / 32, M_ / 32), 256, 0, stream>>>(xi, xiT_bf, M_, D_);

  hipMemcpyAsync(x, x0, SZ * sizeof(float), hipMemcpyDeviceToDevice, stream);

  const int MN = B_ * N_;  // 8192
  for (int step = 0; step < STEPS_; ++step) {
    ln_kernel<<<MN, 256, 0, stream>>>(x, gamma, beta, g_bf);
    // q = g @ Wq^T, k = g @ Wk^T  (NT, B = [768][768] bf16)
    gemm_mfma<0><<<dim3(D_ / 128, MN / 128), 256, 0, stream>>>(g_bf, wq_bf, q, MN, D_, D_, 1.f);
    gemm_mfma<0><<<dim3(D_ / 128, MN / 128), 256, 0, stream>>>(g_bf, wk_bf, kb, MN, D_, D_, 1.f);
    // attention gradient pieces (fp32 math, bf16 outputs)
    attn_pass1<<<dim3(N_ / 64, H_, B_), 256, 0, stream>>>(q, kb, Aq_bf, lse);
    attn_pass2<<<dim3(N_ / 64, H_, B_), 256, 0, stream>>>(q, kb, lse, Ak_bf);
    // Hopfield: x += ALPHA * relu(g @ xi^T) @ xi, chunked rows
    for (int r0 = 0; r0 < MN; r0 += R) {
      const int rows = (MN - r0) < R ? (MN - r0) : R;
      gemm_mfma<1><<<dim3(M_ / 128, rows / 128), 256, 0, stream>>>(
          g_bf + (size_t)r0 * D_, xi_bf, hid_bf, rows, M_, D_, 1.f);
      gemm_mfma<2><<<dim3(D_ / 128, rows / 128), 256, 0, stream>>>(
          hid_bf, xiT_bf, x + (size_t)r0 * D_, rows, D_, M_, ALPHA_);
    }
    // x += ALPHA * (Aq @ Wq + Ak @ Wk)   (NT with pre-transposed weights)
    gemm_mfma<2><<<dim3(D_ / 128, MN / 128), 256, 0, stream>>>(Aq_bf, wqT_bf, x, MN, D_, D_, ALPHA_);
    gemm_mfma<2><<<dim3(D_ / 128, MN / 128), 256, 0, stream>>>(Ak_bf, wkT_bf, x, MN, D_, D_, ALPHA_);
  }
}

// Round 3
// 4485.603 us; speedup vs baseline: 7.1141x; 3.4806x over previous
//
#include <hip/hip_runtime.h>
#include <math.h>

#define B_ 8
#define N_ 1024
#define D_ 768
#define H_ 12
#define Y_ 64
#define M_ 3072
#define STEPS_ 12
#define ALPHA_ 0.1f
#define BETA_ 0.125f
#define EPS_ 1e-5f

typedef __attribute__((ext_vector_type(8))) short bf16x8;
typedef __attribute__((ext_vector_type(8))) unsigned short u16x8;
typedef __attribute__((ext_vector_type(4))) float f32x4;
typedef unsigned short ushort_t;

__device__ inline unsigned short f2bf(float f) {
  union { float f; unsigned int u; } v; v.f = f;
  unsigned int r = (v.u + 0x7fffu + ((v.u >> 16) & 1u)) >> 16;
  return (unsigned short)r;
}

__device__ inline void async_copy16(const void* g, void* l) {
  __builtin_amdgcn_global_load_lds(
      (const __attribute__((address_space(1))) unsigned int*)g,
      (__attribute__((address_space(3))) unsigned int*)l, 16, 0, 0);
}

// ---------------------------------------------------------------------------
// LayerNorm -> bf16 g
// ---------------------------------------------------------------------------
__global__ __launch_bounds__(256) void ln_kernel(const float* __restrict__ x,
    const float* __restrict__ gamma, const float* __restrict__ beta,
    unsigned short* __restrict__ g) {
  const int row = blockIdx.x;
  const int t = threadIdx.x;
  const float* xr = x + (size_t)row * D_;
  float v0 = xr[t], v1 = xr[t + 256], v2 = xr[t + 512];
  float s = v0 + v1 + v2;
  float sq = v0 * v0 + v1 * v1 + v2 * v2;
  #pragma unroll
  for (int off = 1; off < 64; off <<= 1) {
    s += __shfl_xor(s, off);
    sq += __shfl_xor(sq, off);
  }
  __shared__ float ss[4], ssq[4];
  const int wid = t >> 6;
  if ((t & 63) == 0) { ss[wid] = s; ssq[wid] = sq; }
  __syncthreads();
  s = ss[0] + ss[1] + ss[2] + ss[3];
  sq = ssq[0] + ssq[1] + ssq[2] + ssq[3];
  const float mu = s * (1.0f / D_);
  const float var = sq * (1.0f / D_) - mu * mu;
  const float r = rsqrtf(var + EPS_);
  unsigned short* gr = g + (size_t)row * D_;
  gr[t]       = f2bf(gamma[t]       * (v0 - mu) * r + beta[t]);
  gr[t + 256] = f2bf(gamma[t + 256] * (v1 - mu) * r + beta[t + 256]);
  gr[t + 512] = f2bf(gamma[t + 512] * (v2 - mu) * r + beta[t + 512]);
}

__global__ __launch_bounds__(256) void cvt_bf16(const float* __restrict__ in,
    unsigned short* __restrict__ out, int n) {
  int i = blockIdx.x * 256 + threadIdx.x;
  if (i < n) out[i] = f2bf(in[i]);
}

__global__ __launch_bounds__(256) void transpose_cvt(const float* __restrict__ in,
    unsigned short* __restrict__ out, int R, int C) {
  __shared__ float tile[32][33];
  const int c0 = blockIdx.x * 32, r0 = blockIdx.y * 32;
  const int tx = threadIdx.x & 31, ty = threadIdx.x >> 5;
  #pragma unroll
  for (int i = 0; i < 32; i += 8)
    tile[ty + i][tx] = in[(size_t)(r0 + ty + i) * C + c0 + tx];
  __syncthreads();
  #pragma unroll
  for (int i = 0; i < 32; i += 8)
    out[(size_t)(c0 + ty + i) * R + r0 + tx] = f2bf(tile[tx][ty + i]);
}

// ---------------------------------------------------------------------------
// Per-head transpose: in bf16 [B,N,H*Y] -> out bf16 [B,H,Y,N]
// grid (N/64, H, B), 256 threads.
// ---------------------------------------------------------------------------
__global__ __launch_bounds__(256) void transpose_head(
    const unsigned short* __restrict__ in, unsigned short* __restrict__ out) {
  __shared__ unsigned short tile[64][68];
  const int n0 = blockIdx.x * 64;
  const int h = blockIdx.y;
  const int b = blockIdx.z;
  const int t = threadIdx.x;
  {
    const int tok = t >> 2, c0 = (t & 3) * 16;
    const unsigned short* src = in + ((size_t)(b * N_ + n0 + tok)) * D_ + h * Y_ + c0;
    u16x8 v0 = *(const u16x8*)src;
    u16x8 v1 = *(const u16x8*)(src + 8);
    #pragma unroll
    for (int i = 0; i < 8; ++i) {
      tile[tok][c0 + i] = v0[i];
      tile[tok][c0 + 8 + i] = v1[i];
    }
  }
  __syncthreads();
  {
    const int y = t >> 2, tb = (t & 3) * 16;
    u16x8 o0, o1;
    #pragma unroll
    for (int i = 0; i < 8; ++i) {
      o0[i] = tile[tb + i][y];
      o1[i] = tile[tb + 8 + i][y];
    }
    unsigned short* dst = out + ((size_t)((b * H_ + h) * Y_ + y)) * N_ + n0 + tb;
    *(u16x8*)dst = o0;
    *(u16x8*)(dst + 8) = o1;
  }
}

// ---------------------------------------------------------------------------
// bf16 MFMA GEMM, NT: C[M,N] = A[M,K] * B[N,K]^T
// EPI: 0 f32 store, 1 relu bf16 store, 2 C(f32) += alpha*acc, 3 bf16 store
// ---------------------------------------------------------------------------
template <int EPI>
__global__ __launch_bounds__(256) void gemm_mfma(
    const unsigned short* __restrict__ A, const unsigned short* __restrict__ Bm,
    void* __restrict__ Cv, int M, int N, int K, float alpha) {
  __shared__ __align__(16) unsigned short As[128 * 64];
  __shared__ __align__(16) unsigned short Bs[128 * 64];
  const int t = threadIdx.x;
  const int n0 = blockIdx.x * 128;
  const int m0 = blockIdx.y * 128;
  const int w = t >> 6;
  const int l = t & 63;
  const int wr = (w >> 1) * 64;
  const int wc = (w & 1) * 64;

  f32x4 acc[4][4];
  #pragma unroll
  for (int m = 0; m < 4; ++m)
    #pragma unroll
    for (int n = 0; n < 4; ++n) {
      f32x4 z = {0.f, 0.f, 0.f, 0.f};
      acc[m][n] = z;
    }

  for (int kt = 0; kt < K; kt += 64) {
    #pragma unroll
    for (int i = 0; i < 4; ++i) {
      const int flat = i * 4096 + t * 16;
      const int row = flat >> 7;
      const int sphys = (flat >> 4) & 7;
      const int slog = sphys ^ (row & 7);
      async_copy16(A + (size_t)(m0 + row) * K + kt + slog * 8, (char*)As + flat);
      async_copy16(Bm + (size_t)(n0 + row) * K + kt + slog * 8, (char*)Bs + flat);
    }
    __syncthreads();
    #pragma unroll
    for (int kk = 0; kk < 2; ++kk) {
      bf16x8 a[4], b[4];
      const int lr = l & 15;
      const int sl = kk * 4 + (l >> 4);
      #pragma unroll
      for (int m = 0; m < 4; ++m) {
        const int row = wr + m * 16 + lr;
        a[m] = *(const bf16x8*)((const char*)As + row * 128 + ((sl ^ (row & 7)) << 4));
      }
      #pragma unroll
      for (int n = 0; n < 4; ++n) {
        const int row = wc + n * 16 + lr;
        b[n] = *(const bf16x8*)((const char*)Bs + row * 128 + ((sl ^ (row & 7)) << 4));
      }
      #pragma unroll
      for (int m = 0; m < 4; ++m)
        #pragma unroll
        for (int n = 0; n < 4; ++n)
          acc[m][n] = __builtin_amdgcn_mfma_f32_16x16x32_bf16(a[m], b[n], acc[m][n], 0, 0, 0);
    }
    __syncthreads();
  }

  const int cr = (l >> 4) * 4;
  const int cc = l & 15;
  #pragma unroll
  for (int m = 0; m < 4; ++m) {
    #pragma unroll
    for (int n = 0; n < 4; ++n) {
      const int col = n0 + wc + n * 16 + cc;
      #pragma unroll
      for (int j = 0; j < 4; ++j) {
        const int row = m0 + wr + m * 16 + cr + j;
        const float v = acc[m][n][j];
        if (EPI == 0) {
          ((float*)Cv)[(size_t)row * N + col] = v;
        } else if (EPI == 1) {
          ((unsigned short*)Cv)[(size_t)row * N + col] = f2bf(v > 0.f ? v : 0.f);
        } else if (EPI == 3) {
          ((unsigned short*)Cv)[(size_t)row * N + col] = f2bf(v);
        } else {
          float* cp = (float*)Cv + (size_t)row * N + col;
          *cp += alpha * v;
        }
      }
    }
  }
}

// ---------------------------------------------------------------------------
// Attention pass 1 (MFMA flash): per (64-query tile, h, b).
// 4 waves x 16 queries. Iterates 16 key tiles of 64.
//   S-step: A = K tile (LDS, swizzled), B = wave's Q rows (regs)
//           -> lane holds S[key=(l>>4)*4+j+16f][query=l&15]
//   online softmax over keys (lane-local 16 + shfl_xor 16,32)
//   P -> per-wave LDS [query][key] bf16 (8B swizzled writes)
//   PV-step: A = P (LDS), B = K^T tile (LDS, from global kT), acc rows=query
// Outputs Aq bf16 [B,N,D], lse f32 [B,H,N].
// ---------------------------------------------------------------------------
__global__ __launch_bounds__(256) void attn1_mfma(
    const unsigned short* __restrict__ q, const unsigned short* __restrict__ k,
    const unsigned short* __restrict__ kT, unsigned short* __restrict__ Aq,
    float* __restrict__ lse) {
  __shared__ __align__(16) unsigned short Ks[64 * 64];
  __shared__ __align__(16) unsigned short KTs[64 * 64];
  __shared__ __align__(16) unsigned short Ps[4 * 16 * 64];
  const int n0 = blockIdx.x * 64;
  const int h = blockIdx.y;
  const int b = blockIdx.z;
  const int t = threadIdx.x;
  const int w = t >> 6;
  const int l = t & 63;
  const int g = l >> 4;
  const int ql = l & 15;
  char* psw = (char*)(Ps + w * 1024);

  // hoist wave's Q rows (queries n0 + w*16 + ql), B-fragment layout
  bf16x8 qf[2];
  {
    const unsigned short* qrow =
        q + ((size_t)(b * N_ + n0 + w * 16 + ql)) * D_ + h * Y_;
    qf[0] = *(const bf16x8*)(qrow + g * 8);
    qf[1] = *(const bf16x8*)(qrow + 32 + g * 8);
  }
  const unsigned short* kbase = k + (size_t)b * N_ * D_ + h * Y_;
  const unsigned short* kTbase = kT + ((size_t)(b * H_ + h)) * Y_ * N_;

  f32x4 acc[4];
  #pragma unroll
  for (int yf = 0; yf < 4; ++yf) { f32x4 z = {0.f,0.f,0.f,0.f}; acc[yf] = z; }
  float mmax = -1e30f, lsum = 0.f;

  for (int mc = 0; mc < N_; mc += 64) {
    #pragma unroll
    for (int i = 0; i < 2; ++i) {
      const int flat = i * 4096 + t * 16;
      const int row = flat >> 7;
      const int slog = ((flat >> 4) & 7) ^ (row & 7);
      async_copy16(kbase + (size_t)(mc + row) * D_ + slog * 8, (char*)Ks + flat);
    }
    #pragma unroll
    for (int i = 0; i < 2; ++i) {
      const int flat = i * 4096 + t * 16;
      const int row = flat >> 7;
      const int slog = ((flat >> 4) & 7) ^ (row & 7);
      async_copy16(kTbase + (size_t)row * N_ + mc + slog * 8, (char*)KTs + flat);
    }
    __syncthreads();

    // S = K . Q^T  (rows=keys, cols=wave's queries)
    f32x4 s[4];
    #pragma unroll
    for (int f = 0; f < 4; ++f) {
      f32x4 z = {0.f,0.f,0.f,0.f}; s[f] = z;
      #pragma unroll
      for (int ks = 0; ks < 2; ++ks) {
        const int key = f * 16 + ql;
        bf16x8 a = *(const bf16x8*)((const char*)Ks + key * 128 +
                                    (((ks * 4 + g) ^ (key & 7)) << 4));
        s[f] = __builtin_amdgcn_mfma_f32_16x16x32_bf16(a, qf[ks], s[f], 0, 0, 0);
      }
    }
    // online softmax over 16 keys/lane (x4 lane groups)
    float sv[4][4];
    float rm = -1e30f;
    #pragma unroll
    for (int f = 0; f < 4; ++f)
      #pragma unroll
      for (int j = 0; j < 4; ++j) {
        sv[f][j] = s[f][j] * BETA_;
        rm = fmaxf(rm, sv[f][j]);
      }
    rm = fmaxf(rm, __shfl_xor(rm, 16));
    rm = fmaxf(rm, __shfl_xor(rm, 32));
    const float nm = fmaxf(mmax, rm);
    const float sc = __expf(mmax - nm);
    float rs = 0.f;
    float pv[4][4];
    #pragma unroll
    for (int f = 0; f < 4; ++f)
      #pragma unroll
      for (int j = 0; j < 4; ++j) {
        pv[f][j] = __expf(sv[f][j] - nm);
        rs += pv[f][j];
      }
    rs += __shfl_xor(rs, 16);
    rs += __shfl_xor(rs, 32);
    lsum = lsum * sc + rs;
    mmax = nm;
    #pragma unroll
    for (int yf = 0; yf < 4; ++yf) acc[yf] *= sc;
    // write P^T tile: Ps[query ql][key f*16+g*4 .. +3], 8B swizzled
    #pragma unroll
    for (int f = 0; f < 4; ++f) {
      unsigned long long pk =
          (unsigned long long)f2bf(pv[f][0]) |
          ((unsigned long long)f2bf(pv[f][1]) << 16) |
          ((unsigned long long)f2bf(pv[f][2]) << 32) |
          ((unsigned long long)f2bf(pv[f][3]) << 48);
      const int sl = (f * 4 + g) ^ ((ql & 7) << 1);
      *(unsigned long long*)(psw + ql * 128 + sl * 8) = pk;
    }
    // PV: acc[query rows][y cols] += P * K^T
    #pragma unroll
    for (int ks2 = 0; ks2 < 2; ++ks2) {
      const int sl2 = (ks2 * 8 + g * 2) ^ ((ql & 7) << 1);
      bf16x8 pa = *(const bf16x8*)(psw + ql * 128 + sl2 * 8);
      #pragma unroll
      for (int yf = 0; yf < 4; ++yf) {
        const int y = yf * 16 + ql;
        bf16x8 bk = *(const bf16x8*)((const char*)KTs + y * 128 +
                                     (((ks2 * 4 + g) ^ (y & 7)) << 4));
        acc[yf] = __builtin_amdgcn_mfma_f32_16x16x32_bf16(pa, bk, acc[yf], 0, 0, 0);
      }
    }
    __syncthreads();
  }

  // epilogue: rows of acc are queries g*4+j; fetch their lsum via shfl
  float linv[4];
  #pragma unroll
  for (int j = 0; j < 4; ++j)
    linv[j] = 1.0f / __shfl(lsum, (g << 4) + g * 4 + j);
  #pragma unroll
  for (int yf = 0; yf < 4; ++yf)
    #pragma unroll
    for (int j = 0; j < 4; ++j) {
      const int row = n0 + w * 16 + g * 4 + j;
      Aq[((size_t)(b * N_ + row)) * D_ + h * Y_ + yf * 16 + ql] =
          f2bf(acc[yf][j] * linv[j]);
    }
  if (g == 0)
    lse[((size_t)b * H_ + h) * N_ + n0 + w * 16 + ql] = mmax + __logf(lsum);
}

// ---------------------------------------------------------------------------
// Attention pass 2 (MFMA): per (64-key tile, h, b). 4 waves x 16 keys.
//   S-step: A = Q tile (LDS), B = wave's K rows (regs)
//           -> lane holds S[query=(l>>4)*4+j+16f][key=l&15]
//   W = exp(beta*S - lse[query]) -> per-wave LDS [key][query]
//   PV: A = W (LDS), B = Q^T tile (LDS from qT), acc rows=key, cols=y
// ---------------------------------------------------------------------------
__global__ __launch_bounds__(256) void attn2_mfma(
    const unsigned short* __restrict__ q, const unsigned short* __restrict__ k,
    const unsigned short* __restrict__ qT, const float* __restrict__ lse,
    unsigned short* __restrict__ Ak) {
  __shared__ __align__(16) unsigned short Qs[64 * 64];
  __shared__ __align__(16) unsigned short QTs[64 * 64];
  __shared__ __align__(16) unsigned short Ws[4 * 16 * 64];
  __shared__ float lse_s[64];
  const int m0 = blockIdx.x * 64;
  const int h = blockIdx.y;
  const int b = blockIdx.z;
  const int t = threadIdx.x;
  const int w = t >> 6;
  const int l = t & 63;
  const int g = l >> 4;
  const int ql = l & 15;
  char* wsw = (char*)(Ws + w * 1024);

  // hoist wave's K rows (keys m0 + w*16 + ql), B-fragment layout
  bf16x8 ka[2];
  {
    const unsigned short* krow =
        k + ((size_t)(b * N_ + m0 + w * 16 + ql)) * D_ + h * Y_;
    ka[0] = *(const bf16x8*)(krow + g * 8);
    ka[1] = *(const bf16x8*)(krow + 32 + g * 8);
  }
  const unsigned short* qbase = q + (size_t)b * N_ * D_ + h * Y_;
  const unsigned short* qTbase = qT + ((size_t)(b * H_ + h)) * Y_ * N_;
  const float* lbase = lse + ((size_t)b * H_ + h) * N_;

  f32x4 acc[4];
  #pragma unroll
  for (int yf = 0; yf < 4; ++yf) { f32x4 z = {0.f,0.f,0.f,0.f}; acc[yf] = z; }

  for (int nc = 0; nc < N_; nc += 64) {
    #pragma unroll
    for (int i = 0; i < 2; ++i) {
      const int flat = i * 4096 + t * 16;
      const int row = flat >> 7;
      const int slog = ((flat >> 4) & 7) ^ (row & 7);
      async_copy16(qbase + (size_t)(nc + row) * D_ + slog * 8, (char*)Qs + flat);
    }
    #pragma unroll
    for (int i = 0; i < 2; ++i) {
      const int flat = i * 4096 + t * 16;
      const int row = flat >> 7;
      const int slog = ((flat >> 4) & 7) ^ (row & 7);
      async_copy16(qTbase + (size_t)row * N_ + nc + slog * 8, (char*)QTs + flat);
    }
    if (t < 64) lse_s[t] = lbase[nc + t];
    __syncthreads();

    // S^T = Q . K^T (rows=queries, cols=wave's keys)
    f32x4 s[4];
    #pragma unroll
    for (int f = 0; f < 4; ++f) {
      f32x4 z = {0.f,0.f,0.f,0.f}; s[f] = z;
      #pragma unroll
      for (int ks = 0; ks < 2; ++ks) {
        const int qr = f * 16 + ql;
        bf16x8 a = *(const bf16x8*)((const char*)Qs + qr * 128 +
                                    (((ks * 4 + g) ^ (qr & 7)) << 4));
        s[f] = __builtin_amdgcn_mfma_f32_16x16x32_bf16(a, ka[ks], s[f], 0, 0, 0);
      }
    }
    // W = exp(beta*S - lse[query]); write Ws[key ql][query f*16+g*4..+3]
    #pragma unroll
    for (int f = 0; f < 4; ++f) {
      unsigned short w4[4];
      #pragma unroll
      for (int j = 0; j < 4; ++j) {
        const float wv = __expf(s[f][j] * BETA_ - lse_s[f * 16 + g * 4 + j]);
        w4[j] = f2bf(wv);
      }
      unsigned long long pk =
          (unsigned long long)w4[0] | ((unsigned long long)w4[1] << 16) |
          ((unsigned long long)w4[2] << 32) | ((unsigned long long)w4[3] << 48);
      const int sl = (f * 4 + g) ^ ((ql & 7) << 1);
      *(unsigned long long*)(wsw + ql * 128 + sl * 8) = pk;
    }
    // PV: acc[key rows][y cols] += W * Q^T
    #pragma unroll
    for (int ks2 = 0; ks2 < 2; ++ks2) {
      const int sl2 = (ks2 * 8 + g * 2) ^ ((ql & 7) << 1);
      bf16x8 wa = *(const bf16x8*)(wsw + ql * 128 + sl2 * 8);
      #pragma unroll
      for (int yf = 0; yf < 4; ++yf) {
        const int y = yf * 16 + ql;
        bf16x8 bq = *(const bf16x8*)((const char*)QTs + y * 128 +
                                     (((ks2 * 4 + g) ^ (y & 7)) << 4));
        acc[yf] = __builtin_amdgcn_mfma_f32_16x16x32_bf16(wa, bq, acc[yf], 0, 0, 0);
      }
    }
    __syncthreads();
  }

  #pragma unroll
  for (int yf = 0; yf < 4; ++yf)
    #pragma unroll
    for (int j = 0; j < 4; ++j) {
      const int row = m0 + w * 16 + g * 4 + j;
      Ak[((size_t)(b * N_ + row)) * D_ + h * Y_ + yf * 16 + ql] =
          f2bf(acc[yf][j]);
    }
}

// ---------------------------------------------------------------------------
extern "C" void kernel_launch(void* const* d_in, const int* in_sizes, int n_in,
                              void* d_out, int out_size, void* d_ws, size_t ws_size,
                              hipStream_t stream) {
  const float* x0    = (const float*)d_in[0];
  const float* gamma = (const float*)d_in[1];
  const float* beta  = (const float*)d_in[2];
  const float* wq    = (const float*)d_in[3];
  const float* wk    = (const float*)d_in[4];
  const float* xi    = (const float*)d_in[5];
  float* x = (float*)d_out;

  const size_t SZ = (size_t)B_ * N_ * D_;   // 6291456
  char* wsp = (char*)d_ws;
  size_t off = 0;
  auto alloc = [&](size_t bytes) -> void* {
    off = (off + 255) & ~(size_t)255;
    void* p = wsp + off;
    off += bytes;
    return p;
  };
  unsigned short* g_bf  = (unsigned short*)alloc(SZ * 2);
  unsigned short* q_bf  = (unsigned short*)alloc(SZ * 2);
  unsigned short* k_bf  = (unsigned short*)alloc(SZ * 2);
  unsigned short* qT_bf = (unsigned short*)alloc(SZ * 2);
  unsigned short* kT_bf = (unsigned short*)alloc(SZ * 2);
  unsigned short* Aq_bf = (unsigned short*)alloc(SZ * 2);
  unsigned short* Ak_bf = (unsigned short*)alloc(SZ * 2);
  float*          lse   = (float*)alloc((size_t)B_ * H_ * N_ * 4);
  unsigned short* wq_bf  = (unsigned short*)alloc((size_t)D_ * D_ * 2);
  unsigned short* wk_bf  = (unsigned short*)alloc((size_t)D_ * D_ * 2);
  unsigned short* wqT_bf = (unsigned short*)alloc((size_t)D_ * D_ * 2);
  unsigned short* wkT_bf = (unsigned short*)alloc((size_t)D_ * D_ * 2);
  unsigned short* xi_bf  = (unsigned short*)alloc((size_t)M_ * D_ * 2);
  unsigned short* xiT_bf = (unsigned short*)alloc((size_t)M_ * D_ * 2);
  off = (off + 255) & ~(size_t)255;
  unsigned short* hid_bf = (unsigned short*)(wsp + off);
  size_t avail = ws_size > off ? ws_size - off : 0;
  long rmax = (long)(avail / ((size_t)M_ * 2));
  int R = (int)((rmax / 128) * 128);
  if (R > B_ * N_) R = B_ * N_;
  if (R < 128) R = 128;

  const int WQN = D_ * D_;
  const int XIN = M_ * D_;
  cvt_bf16<<<(WQN + 255) / 256, 256, 0, stream>>>(wq, wq_bf, WQN);
  cvt_bf16<<<(WQN + 255) / 256, 256, 0, stream>>>(wk, wk_bf, WQN);
  cvt_bf16<<<(XIN + 255) / 256, 256, 0, stream>>>(xi, xi_bf, XIN);
  transpose_cvt<<<dim3(D_ / 32, D_ / 32), 256, 0, stream>>>(wq, wqT_bf, D_, D_);
  transpose_cvt<<<dim3(D_ / 32, D_ / 32), 256, 0, stream>>>(wk, wkT_bf, D_, D_);
  transpose_cvt<<<dim3(D_ / 32, M_ / 32), 256, 0, stream>>>(xi, xiT_bf, M_, D_);

  hipMemcpyAsync(x, x0, SZ * sizeof(float), hipMemcpyDeviceToDevice, stream);

  const int MN = B_ * N_;  // 8192
  for (int step = 0; step < STEPS_; ++step) {
    ln_kernel<<<MN, 256, 0, stream>>>(x, gamma, beta, g_bf);
    // q = g @ Wq^T, k = g @ Wk^T  -> bf16
    gemm_mfma<3><<<dim3(D_ / 128, MN / 128), 256, 0, stream>>>(g_bf, wq_bf, q_bf, MN, D_, D_, 1.f);
    gemm_mfma<3><<<dim3(D_ / 128, MN / 128), 256, 0, stream>>>(g_bf, wk_bf, k_bf, MN, D_, D_, 1.f);
    // head transposes for attention B-operands
    transpose_head<<<dim3(N_ / 64, H_, B_), 256, 0, stream>>>(q_bf, qT_bf);
    transpose_head<<<dim3(N_ / 64, H_, B_), 256, 0, stream>>>(k_bf, kT_bf);
    // attention gradient pieces
    attn1_mfma<<<dim3(N_ / 64, H_, B_), 256, 0, stream>>>(q_bf, k_bf, kT_bf, Aq_bf, lse);
    attn2_mfma<<<dim3(N_ / 64, H_, B_), 256, 0, stream>>>(q_bf, k_bf, qT_bf, lse, Ak_bf);
    // Hopfield: x += ALPHA * relu(g @ xi^T) @ xi, chunked rows
    for (int r0 = 0; r0 < MN; r0 += R) {
      const int rows = (MN - r0) < R ? (MN - r0) : R;
      gemm_mfma<1><<<dim3(M_ / 128, rows / 128), 256, 0, stream>>>(
          g_bf + (size_t)r0 * D_, xi_bf, hid_bf, rows, M_, D_, 1.f);
      gemm_mfma<2><<<dim3(D_ / 128, rows / 128), 256, 0, stream>>>(
          hid_bf, xiT_bf, x + (size_t)r0 * D_, rows, D_, M_, ALPHA_);
    }
    // x += ALPHA * (Aq @ Wq + Ak @ Wk)
    gemm_mfma<2><<<dim3(D_ / 128, MN / 128), 256, 0, stream>>>(Aq_bf, wqT_bf, x, MN, D_, D_, ALPHA_);
    gemm_mfma<2><<<dim3(D_ / 128, MN / 128), 256, 0, stream>>>(Ak_bf, wkT_bf, x, MN, D_, D_, ALPHA_);
  }
}

// Round 4
// 3338.132 us; speedup vs baseline: 9.5596x; 1.3437x over previous
//
#include <hip/hip_runtime.h>
#include <math.h>

#define B_ 8
#define N_ 1024
#define D_ 768
#define H_ 12
#define Y_ 64
#define M_ 3072
#define STEPS_ 12
#define ALPHA_ 0.1f
#define BETA_ 0.125f
#define EPS_ 1e-5f

typedef __attribute__((ext_vector_type(8))) short bf16x8;
typedef __attribute__((ext_vector_type(8))) unsigned short u16x8;
typedef __attribute__((ext_vector_type(4))) float f32x4;

__device__ inline unsigned short f2bf(float f) {
  union { float f; unsigned int u; } v; v.f = f;
  unsigned int r = (v.u + 0x7fffu + ((v.u >> 16) & 1u)) >> 16;
  return (unsigned short)r;
}

__device__ inline void async_copy16(const void* g, void* l) {
  __builtin_amdgcn_global_load_lds(
      (const __attribute__((address_space(1))) unsigned int*)g,
      (__attribute__((address_space(3))) unsigned int*)l, 16, 0, 0);
}

// bijective XCD-aware remap of a 1D grid (m204 formula)
__device__ inline int xcd_remap(int bid, int nwg) {
  const int qd = nwg >> 3, rm = nwg & 7;
  const int xcd = bid & 7, idx = bid >> 3;
  return (xcd < rm ? xcd * (qd + 1) : rm * (qd + 1) + (xcd - rm) * qd) + idx;
}

// ---------------------------------------------------------------------------
// LayerNorm -> bf16 g
// ---------------------------------------------------------------------------
__global__ __launch_bounds__(256) void ln_kernel(const float* __restrict__ x,
    const float* __restrict__ gamma, const float* __restrict__ beta,
    unsigned short* __restrict__ g) {
  const int row = blockIdx.x;
  const int t = threadIdx.x;
  const float* xr = x + (size_t)row * D_;
  float v0 = xr[t], v1 = xr[t + 256], v2 = xr[t + 512];
  float s = v0 + v1 + v2;
  float sq = v0 * v0 + v1 * v1 + v2 * v2;
  #pragma unroll
  for (int off = 1; off < 64; off <<= 1) {
    s += __shfl_xor(s, off);
    sq += __shfl_xor(sq, off);
  }
  __shared__ float ss[4], ssq[4];
  const int wid = t >> 6;
  if ((t & 63) == 0) { ss[wid] = s; ssq[wid] = sq; }
  __syncthreads();
  s = ss[0] + ss[1] + ss[2] + ss[3];
  sq = ssq[0] + ssq[1] + ssq[2] + ssq[3];
  const float mu = s * (1.0f / D_);
  const float var = sq * (1.0f / D_) - mu * mu;
  const float r = rsqrtf(var + EPS_);
  unsigned short* gr = g + (size_t)row * D_;
  gr[t]       = f2bf(gamma[t]       * (v0 - mu) * r + beta[t]);
  gr[t + 256] = f2bf(gamma[t + 256] * (v1 - mu) * r + beta[t + 256]);
  gr[t + 512] = f2bf(gamma[t + 512] * (v2 - mu) * r + beta[t + 512]);
}

__global__ __launch_bounds__(256) void cvt_bf16(const float* __restrict__ in,
    unsigned short* __restrict__ out, int n) {
  int i = blockIdx.x * 256 + threadIdx.x;
  if (i < n) out[i] = f2bf(in[i]);
}

// transpose + convert: in[R][C] f32 -> out[c][koff + r] bf16 with row stride ldo
__global__ __launch_bounds__(256) void transpose_cvt(const float* __restrict__ in,
    unsigned short* __restrict__ out, int R, int C, int ldo, int koff) {
  __shared__ float tile[32][33];
  const int c0 = blockIdx.x * 32, r0 = blockIdx.y * 32;
  const int tx = threadIdx.x & 31, ty = threadIdx.x >> 5;
  #pragma unroll
  for (int i = 0; i < 32; i += 8)
    tile[ty + i][tx] = in[(size_t)(r0 + ty + i) * C + c0 + tx];
  __syncthreads();
  #pragma unroll
  for (int i = 0; i < 32; i += 8)
    out[(size_t)(c0 + ty + i) * ldo + koff + r0 + tx] = f2bf(tile[tx][ty + i]);
}

// ---------------------------------------------------------------------------
// Per-head transpose: in bf16 [B,N,ld] (+coff) -> out bf16 [B,H,Y,N]
// ---------------------------------------------------------------------------
__global__ __launch_bounds__(256) void transpose_head(
    const unsigned short* __restrict__ in, int ld, int coff,
    unsigned short* __restrict__ out) {
  __shared__ unsigned short tile[64][68];
  const int n0 = blockIdx.x * 64;
  const int h = blockIdx.y;
  const int b = blockIdx.z;
  const int t = threadIdx.x;
  {
    const int tok = t >> 2, c0 = (t & 3) * 16;
    const unsigned short* src = in + ((size_t)(b * N_ + n0 + tok)) * ld + coff + h * Y_ + c0;
    u16x8 v0 = *(const u16x8*)src;
    u16x8 v1 = *(const u16x8*)(src + 8);
    #pragma unroll
    for (int i = 0; i < 8; ++i) {
      tile[tok][c0 + i] = v0[i];
      tile[tok][c0 + 8 + i] = v1[i];
    }
  }
  __syncthreads();
  {
    const int y = t >> 2, tb = (t & 3) * 16;
    u16x8 o0, o1;
    #pragma unroll
    for (int i = 0; i < 8; ++i) {
      o0[i] = tile[tb + i][y];
      o1[i] = tile[tb + 8 + i][y];
    }
    unsigned short* dst = out + ((size_t)((b * H_ + h) * Y_ + y)) * N_ + n0 + tb;
    *(u16x8*)dst = o0;
    *(u16x8*)(dst + 8) = o1;
  }
}

// ---------------------------------------------------------------------------
// bf16 MFMA GEMM 128x128, NT: C[*,N] = A[*,K] * B[N,K]^T, bf16 out (opt relu)
// 1D grid (XCD-swizzled), gridN = N/128.
// ---------------------------------------------------------------------------
template <bool RELU>
__global__ __launch_bounds__(256) void gemm128(
    const unsigned short* __restrict__ A, const unsigned short* __restrict__ Bm,
    unsigned short* __restrict__ C, int N, int K, int gridN) {
  __shared__ __align__(16) unsigned short As[128 * 64];
  __shared__ __align__(16) unsigned short Bs[128 * 64];
  const int t = threadIdx.x;
  const int f = xcd_remap(blockIdx.x, gridDim.x);
  const int n0 = (f % gridN) * 128;
  const int m0 = (f / gridN) * 128;
  const int w = t >> 6;
  const int l = t & 63;
  const int wr = (w >> 1) * 64;
  const int wc = (w & 1) * 64;

  f32x4 acc[4][4];
  #pragma unroll
  for (int m = 0; m < 4; ++m)
    #pragma unroll
    for (int n = 0; n < 4; ++n) {
      f32x4 z = {0.f, 0.f, 0.f, 0.f};
      acc[m][n] = z;
    }

  for (int kt = 0; kt < K; kt += 64) {
    #pragma unroll
    for (int i = 0; i < 4; ++i) {
      const int flat = i * 4096 + t * 16;
      const int row = flat >> 7;
      const int slog = ((flat >> 4) & 7) ^ (row & 7);
      async_copy16(A + (size_t)(m0 + row) * K + kt + slog * 8, (char*)As + flat);
      async_copy16(Bm + (size_t)(n0 + row) * K + kt + slog * 8, (char*)Bs + flat);
    }
    __syncthreads();
    #pragma unroll
    for (int kk = 0; kk < 2; ++kk) {
      bf16x8 a[4], b[4];
      const int lr = l & 15;
      const int sl = kk * 4 + (l >> 4);
      #pragma unroll
      for (int m = 0; m < 4; ++m) {
        const int row = wr + m * 16 + lr;
        a[m] = *(const bf16x8*)((const char*)As + row * 128 + ((sl ^ (row & 7)) << 4));
      }
      #pragma unroll
      for (int n = 0; n < 4; ++n) {
        const int row = wc + n * 16 + lr;
        b[n] = *(const bf16x8*)((const char*)Bs + row * 128 + ((sl ^ (row & 7)) << 4));
      }
      #pragma unroll
      for (int m = 0; m < 4; ++m)
        #pragma unroll
        for (int n = 0; n < 4; ++n)
          acc[m][n] = __builtin_amdgcn_mfma_f32_16x16x32_bf16(a[m], b[n], acc[m][n], 0, 0, 0);
    }
    __syncthreads();
  }

  const int cr = (l >> 4) * 4;
  const int cc = l & 15;
  #pragma unroll
  for (int m = 0; m < 4; ++m)
    #pragma unroll
    for (int n = 0; n < 4; ++n) {
      const int col = n0 + wc + n * 16 + cc;
      #pragma unroll
      for (int j = 0; j < 4; ++j) {
        const int row = m0 + wr + m * 16 + cr + j;
        float v = acc[m][n][j];
        if (RELU) v = v > 0.f ? v : 0.f;
        C[(size_t)row * N + col] = f2bf(v);
      }
    }
}

// ---------------------------------------------------------------------------
// Fused update GEMM: x[m][n] += alpha * sum_k Acat[m][k] * B2[n][k]
// Acat = [AqAk (ld 1536) | hid (ld 3072)] split at k=1536; K=4608, N=768.
// BM=128, BN=64, 1D grid (XCD-swizzled), gridN = 12.
// ---------------------------------------------------------------------------
__global__ __launch_bounds__(256) void gemm_update(
    const unsigned short* __restrict__ A1,  // AqAk chunk base, ld 1536
    const unsigned short* __restrict__ A2,  // hid chunk base, ld 3072
    const unsigned short* __restrict__ B2,  // [768][4608]
    float* __restrict__ x,                  // chunk base, ld 768
    float alpha) {
  __shared__ __align__(16) unsigned short As[128 * 64];
  __shared__ __align__(16) unsigned short Bs[64 * 64];
  const int t = threadIdx.x;
  const int f = xcd_remap(blockIdx.x, gridDim.x);
  const int n0 = (f % 12) * 64;
  const int m0 = (f / 12) * 128;
  const int w = t >> 6;
  const int l = t & 63;
  const int wr = (w >> 1) * 64;
  const int wc = (w & 1) * 32;

  f32x4 acc[4][2];
  #pragma unroll
  for (int m = 0; m < 4; ++m)
    #pragma unroll
    for (int n = 0; n < 2; ++n) {
      f32x4 z = {0.f, 0.f, 0.f, 0.f};
      acc[m][n] = z;
    }

  for (int kt = 0; kt < 4608; kt += 64) {
    #pragma unroll
    for (int i = 0; i < 4; ++i) {
      const int flat = i * 4096 + t * 16;
      const int row = flat >> 7;
      const int slog = ((flat >> 4) & 7) ^ (row & 7);
      const unsigned short* src = (kt < 1536)
          ? A1 + (size_t)(m0 + row) * 1536 + kt + slog * 8
          : A2 + (size_t)(m0 + row) * 3072 + (kt - 1536) + slog * 8;
      async_copy16(src, (char*)As + flat);
    }
    #pragma unroll
    for (int i = 0; i < 2; ++i) {
      const int flat = i * 4096 + t * 16;
      const int row = flat >> 7;
      const int slog = ((flat >> 4) & 7) ^ (row & 7);
      async_copy16(B2 + (size_t)(n0 + row) * 4608 + kt + slog * 8, (char*)Bs + flat);
    }
    __syncthreads();
    #pragma unroll
    for (int kk = 0; kk < 2; ++kk) {
      bf16x8 a[4], b[2];
      const int lr = l & 15;
      const int sl = kk * 4 + (l >> 4);
      #pragma unroll
      for (int m = 0; m < 4; ++m) {
        const int row = wr + m * 16 + lr;
        a[m] = *(const bf16x8*)((const char*)As + row * 128 + ((sl ^ (row & 7)) << 4));
      }
      #pragma unroll
      for (int n = 0; n < 2; ++n) {
        const int row = wc + n * 16 + lr;
        b[n] = *(const bf16x8*)((const char*)Bs + row * 128 + ((sl ^ (row & 7)) << 4));
      }
      #pragma unroll
      for (int m = 0; m < 4; ++m)
        #pragma unroll
        for (int n = 0; n < 2; ++n)
          acc[m][n] = __builtin_amdgcn_mfma_f32_16x16x32_bf16(a[m], b[n], acc[m][n], 0, 0, 0);
    }
    __syncthreads();
  }

  const int cr = (l >> 4) * 4;
  const int cc = l & 15;
  #pragma unroll
  for (int m = 0; m < 4; ++m)
    #pragma unroll
    for (int n = 0; n < 2; ++n) {
      const int col = n0 + wc + n * 16 + cc;
      #pragma unroll
      for (int j = 0; j < 4; ++j) {
        const int row = m0 + wr + m * 16 + cr + j;
        float* cp = x + (size_t)row * 768 + col;
        *cp += alpha * acc[m][n][j];
      }
    }
}

// ---------------------------------------------------------------------------
// Attention pass 1 (MFMA flash). q/k strided in qk (ld 1536, k at +768);
// Aq out into AqAk (ld 1536, offset 0). lse f32 [B,H,N].
// ---------------------------------------------------------------------------
__global__ __launch_bounds__(256) void attn1_mfma(
    const unsigned short* __restrict__ qk, const unsigned short* __restrict__ kT,
    unsigned short* __restrict__ AqAk, float* __restrict__ lse) {
  __shared__ __align__(16) unsigned short Ks[64 * 64];
  __shared__ __align__(16) unsigned short KTs[64 * 64];
  __shared__ __align__(16) unsigned short Ps[4 * 16 * 64];
  const int n0 = blockIdx.x * 64;
  const int h = blockIdx.y;
  const int b = blockIdx.z;
  const int t = threadIdx.x;
  const int w = t >> 6;
  const int l = t & 63;
  const int g = l >> 4;
  const int ql = l & 15;
  char* psw = (char*)(Ps + w * 1024);
  const int LD = 1536;

  bf16x8 qf[2];
  {
    const unsigned short* qrow =
        qk + ((size_t)(b * N_ + n0 + w * 16 + ql)) * LD + h * Y_;
    qf[0] = *(const bf16x8*)(qrow + g * 8);
    qf[1] = *(const bf16x8*)(qrow + 32 + g * 8);
  }
  const unsigned short* kbase = qk + (size_t)b * N_ * LD + 768 + h * Y_;
  const unsigned short* kTbase = kT + ((size_t)(b * H_ + h)) * Y_ * N_;

  f32x4 acc[4];
  #pragma unroll
  for (int yf = 0; yf < 4; ++yf) { f32x4 z = {0.f,0.f,0.f,0.f}; acc[yf] = z; }
  float mmax = -1e30f, lsum = 0.f;

  for (int mc = 0; mc < N_; mc += 64) {
    #pragma unroll
    for (int i = 0; i < 2; ++i) {
      const int flat = i * 4096 + t * 16;
      const int row = flat >> 7;
      const int slog = ((flat >> 4) & 7) ^ (row & 7);
      async_copy16(kbase + (size_t)(mc + row) * LD + slog * 8, (char*)Ks + flat);
    }
    #pragma unroll
    for (int i = 0; i < 2; ++i) {
      const int flat = i * 4096 + t * 16;
      const int row = flat >> 7;
      const int slog = ((flat >> 4) & 7) ^ (row & 7);
      async_copy16(kTbase + (size_t)row * N_ + mc + slog * 8, (char*)KTs + flat);
    }
    __syncthreads();

    f32x4 s[4];
    #pragma unroll
    for (int f = 0; f < 4; ++f) {
      f32x4 z = {0.f,0.f,0.f,0.f}; s[f] = z;
      #pragma unroll
      for (int ks = 0; ks < 2; ++ks) {
        const int key = f * 16 + ql;
        bf16x8 a = *(const bf16x8*)((const char*)Ks + key * 128 +
                                    (((ks * 4 + g) ^ (key & 7)) << 4));
        s[f] = __builtin_amdgcn_mfma_f32_16x16x32_bf16(a, qf[ks], s[f], 0, 0, 0);
      }
    }
    float sv[4][4];
    float rm = -1e30f;
    #pragma unroll
    for (int f = 0; f < 4; ++f)
      #pragma unroll
      for (int j = 0; j < 4; ++j) {
        sv[f][j] = s[f][j] * BETA_;
        rm = fmaxf(rm, sv[f][j]);
      }
    rm = fmaxf(rm, __shfl_xor(rm, 16));
    rm = fmaxf(rm, __shfl_xor(rm, 32));
    const float nm = fmaxf(mmax, rm);
    const float sc = __expf(mmax - nm);
    float rs = 0.f;
    float pv[4][4];
    #pragma unroll
    for (int f = 0; f < 4; ++f)
      #pragma unroll
      for (int j = 0; j < 4; ++j) {
        pv[f][j] = __expf(sv[f][j] - nm);
        rs += pv[f][j];
      }
    rs += __shfl_xor(rs, 16);
    rs += __shfl_xor(rs, 32);
    lsum = lsum * sc + rs;
    mmax = nm;
    #pragma unroll
    for (int yf = 0; yf < 4; ++yf) acc[yf] *= sc;
    #pragma unroll
    for (int f = 0; f < 4; ++f) {
      unsigned long long pk =
          (unsigned long long)f2bf(pv[f][0]) |
          ((unsigned long long)f2bf(pv[f][1]) << 16) |
          ((unsigned long long)f2bf(pv[f][2]) << 32) |
          ((unsigned long long)f2bf(pv[f][3]) << 48);
      const int sl = (f * 4 + g) ^ ((ql & 7) << 1);
      *(unsigned long long*)(psw + ql * 128 + sl * 8) = pk;
    }
    #pragma unroll
    for (int ks2 = 0; ks2 < 2; ++ks2) {
      const int sl2 = (ks2 * 8 + g * 2) ^ ((ql & 7) << 1);
      bf16x8 pa = *(const bf16x8*)(psw + ql * 128 + sl2 * 8);
      #pragma unroll
      for (int yf = 0; yf < 4; ++yf) {
        const int y = yf * 16 + ql;
        bf16x8 bk = *(const bf16x8*)((const char*)KTs + y * 128 +
                                     (((ks2 * 4 + g) ^ (y & 7)) << 4));
        acc[yf] = __builtin_amdgcn_mfma_f32_16x16x32_bf16(pa, bk, acc[yf], 0, 0, 0);
      }
    }
    __syncthreads();
  }

  float linv[4];
  #pragma unroll
  for (int j = 0; j < 4; ++j)
    linv[j] = 1.0f / __shfl(lsum, (g << 4) + g * 4 + j);
  #pragma unroll
  for (int yf = 0; yf < 4; ++yf)
    #pragma unroll
    for (int j = 0; j < 4; ++j) {
      const int row = n0 + w * 16 + g * 4 + j;
      AqAk[((size_t)(b * N_ + row)) * LD + h * Y_ + yf * 16 + ql] =
          f2bf(acc[yf][j] * linv[j]);
    }
  if (g == 0)
    lse[((size_t)b * H_ + h) * N_ + n0 + w * 16 + ql] = mmax + __logf(lsum);
}

// ---------------------------------------------------------------------------
// Attention pass 2 (MFMA). Ak out into AqAk (ld 1536, offset 768).
// ---------------------------------------------------------------------------
__global__ __launch_bounds__(256) void attn2_mfma(
    const unsigned short* __restrict__ qk, const unsigned short* __restrict__ qT,
    const float* __restrict__ lse, unsigned short* __restrict__ AqAk) {
  __shared__ __align__(16) unsigned short Qs[64 * 64];
  __shared__ __align__(16) unsigned short QTs[64 * 64];
  __shared__ __align__(16) unsigned short Ws[4 * 16 * 64];
  __shared__ float lse_s[64];
  const int m0 = blockIdx.x * 64;
  const int h = blockIdx.y;
  const int b = blockIdx.z;
  const int t = threadIdx.x;
  const int w = t >> 6;
  const int l = t & 63;
  const int g = l >> 4;
  const int ql = l & 15;
  char* wsw = (char*)(Ws + w * 1024);
  const int LD = 1536;

  bf16x8 ka[2];
  {
    const unsigned short* krow =
        qk + ((size_t)(b * N_ + m0 + w * 16 + ql)) * LD + 768 + h * Y_;
    ka[0] = *(const bf16x8*)(krow + g * 8);
    ka[1] = *(const bf16x8*)(krow + 32 + g * 8);
  }
  const unsigned short* qbase = qk + (size_t)b * N_ * LD + h * Y_;
  const unsigned short* qTbase = qT + ((size_t)(b * H_ + h)) * Y_ * N_;
  const float* lbase = lse + ((size_t)b * H_ + h) * N_;

  f32x4 acc[4];
  #pragma unroll
  for (int yf = 0; yf < 4; ++yf) { f32x4 z = {0.f,0.f,0.f,0.f}; acc[yf] = z; }

  for (int nc = 0; nc < N_; nc += 64) {
    #pragma unroll
    for (int i = 0; i < 2; ++i) {
      const int flat = i * 4096 + t * 16;
      const int row = flat >> 7;
      const int slog = ((flat >> 4) & 7) ^ (row & 7);
      async_copy16(qbase + (size_t)(nc + row) * LD + slog * 8, (char*)Qs + flat);
    }
    #pragma unroll
    for (int i = 0; i < 2; ++i) {
      const int flat = i * 4096 + t * 16;
      const int row = flat >> 7;
      const int slog = ((flat >> 4) & 7) ^ (row & 7);
      async_copy16(qTbase + (size_t)row * N_ + nc + slog * 8, (char*)QTs + flat);
    }
    if (t < 64) lse_s[t] = lbase[nc + t];
    __syncthreads();

    f32x4 s[4];
    #pragma unroll
    for (int f = 0; f < 4; ++f) {
      f32x4 z = {0.f,0.f,0.f,0.f}; s[f] = z;
      #pragma unroll
      for (int ks = 0; ks < 2; ++ks) {
        const int qr = f * 16 + ql;
        bf16x8 a = *(const bf16x8*)((const char*)Qs + qr * 128 +
                                    (((ks * 4 + g) ^ (qr & 7)) << 4));
        s[f] = __builtin_amdgcn_mfma_f32_16x16x32_bf16(a, ka[ks], s[f], 0, 0, 0);
      }
    }
    #pragma unroll
    for (int f = 0; f < 4; ++f) {
      unsigned short w4[4];
      #pragma unroll
      for (int j = 0; j < 4; ++j) {
        const float wv = __expf(s[f][j] * BETA_ - lse_s[f * 16 + g * 4 + j]);
        w4[j] = f2bf(wv);
      }
      unsigned long long pk =
          (unsigned long long)w4[0] | ((unsigned long long)w4[1] << 16) |
          ((unsigned long long)w4[2] << 32) | ((unsigned long long)w4[3] << 48);
      const int sl = (f * 4 + g) ^ ((ql & 7) << 1);
      *(unsigned long long*)(wsw + ql * 128 + sl * 8) = pk;
    }
    #pragma unroll
    for (int ks2 = 0; ks2 < 2; ++ks2) {
      const int sl2 = (ks2 * 8 + g * 2) ^ ((ql & 7) << 1);
      bf16x8 wa = *(const bf16x8*)(wsw + ql * 128 + sl2 * 8);
      #pragma unroll
      for (int yf = 0; yf < 4; ++yf) {
        const int y = yf * 16 + ql;
        bf16x8 bq = *(const bf16x8*)((const char*)QTs + y * 128 +
                                     (((ks2 * 4 + g) ^ (y & 7)) << 4));
        acc[yf] = __builtin_amdgcn_mfma_f32_16x16x32_bf16(wa, bq, acc[yf], 0, 0, 0);
      }
    }
    __syncthreads();
  }

  #pragma unroll
  for (int yf = 0; yf < 4; ++yf)
    #pragma unroll
    for (int j = 0; j < 4; ++j) {
      const int row = m0 + w * 16 + g * 4 + j;
      AqAk[((size_t)(b * N_ + row)) * LD + 768 + h * Y_ + yf * 16 + ql] =
          f2bf(acc[yf][j]);
    }
}

// ---------------------------------------------------------------------------
extern "C" void kernel_launch(void* const* d_in, const int* in_sizes, int n_in,
                              void* d_out, int out_size, void* d_ws, size_t ws_size,
                              hipStream_t stream) {
  const float* x0    = (const float*)d_in[0];
  const float* gamma = (const float*)d_in[1];
  const float* beta  = (const float*)d_in[2];
  const float* wq    = (const float*)d_in[3];
  const float* wk    = (const float*)d_in[4];
  const float* xi    = (const float*)d_in[5];
  float* x = (float*)d_out;

  const size_t SZ = (size_t)B_ * N_ * D_;   // 6291456
  char* wsp = (char*)d_ws;
  size_t off = 0;
  auto alloc = [&](size_t bytes) -> void* {
    off = (off + 255) & ~(size_t)255;
    void* p = wsp + off;
    off += bytes;
    return p;
  };
  unsigned short* g_bf   = (unsigned short*)alloc(SZ * 2);
  unsigned short* qk_bf  = (unsigned short*)alloc(SZ * 2 * 2);        // [8192][1536]
  unsigned short* AqAk   = (unsigned short*)alloc(SZ * 2 * 2);        // [8192][1536]
  unsigned short* qT_bf  = (unsigned short*)alloc(SZ * 2);
  unsigned short* kT_bf  = (unsigned short*)alloc(SZ * 2);
  float*          lse    = (float*)alloc((size_t)B_ * H_ * N_ * 4);
  unsigned short* wqk_bf = (unsigned short*)alloc((size_t)2 * D_ * D_ * 2);   // [1536][768]
  unsigned short* xi_bf  = (unsigned short*)alloc((size_t)M_ * D_ * 2);       // [3072][768]
  unsigned short* B2_bf  = (unsigned short*)alloc((size_t)D_ * (2 * D_ + M_) * 2); // [768][4608]
  off = (off + 255) & ~(size_t)255;
  unsigned short* hid_bf = (unsigned short*)(wsp + off);
  size_t avail = ws_size > off ? ws_size - off : 0;
  long rmax = (long)(avail / ((size_t)M_ * 2));
  int R = (int)((rmax / 128) * 128);
  if (R > B_ * N_) R = B_ * N_;
  if (R < 128) R = 128;

  const int WQN = D_ * D_;
  const int XIN = M_ * D_;
  // B1 for proj: [wq; wk] rows
  cvt_bf16<<<(WQN + 255) / 256, 256, 0, stream>>>(wq, wqk_bf, WQN);
  cvt_bf16<<<(WQN + 255) / 256, 256, 0, stream>>>(wk, wqk_bf + (size_t)D_ * D_, WQN);
  cvt_bf16<<<(XIN + 255) / 256, 256, 0, stream>>>(xi, xi_bf, XIN);
  // B2 = [wqT | wkT | xiT] along k, ld 4608
  const int LDB2 = 2 * D_ + M_;  // 4608
  transpose_cvt<<<dim3(D_ / 32, D_ / 32), 256, 0, stream>>>(wq, B2_bf, D_, D_, LDB2, 0);
  transpose_cvt<<<dim3(D_ / 32, D_ / 32), 256, 0, stream>>>(wk, B2_bf, D_, D_, LDB2, D_);
  transpose_cvt<<<dim3(D_ / 32, M_ / 32), 256, 0, stream>>>(xi, B2_bf, M_, D_, LDB2, 2 * D_);

  hipMemcpyAsync(x, x0, SZ * sizeof(float), hipMemcpyDeviceToDevice, stream);

  const int MN = B_ * N_;  // 8192
  for (int step = 0; step < STEPS_; ++step) {
    ln_kernel<<<MN, 256, 0, stream>>>(x, gamma, beta, g_bf);
    // qk = g @ [Wq;Wk]^T  -> [8192][1536] bf16
    gemm128<false><<<(1536 / 128) * (MN / 128), 256, 0, stream>>>(
        g_bf, wqk_bf, qk_bf, 1536, D_, 1536 / 128);
    // head transposes for attention B-operands
    transpose_head<<<dim3(N_ / 64, H_, B_), 256, 0, stream>>>(qk_bf, 1536, 0, qT_bf);
    transpose_head<<<dim3(N_ / 64, H_, B_), 256, 0, stream>>>(qk_bf, 1536, 768, kT_bf);
    // attention gradient pieces -> AqAk
    attn1_mfma<<<dim3(N_ / 64, H_, B_), 256, 0, stream>>>(qk_bf, kT_bf, AqAk, lse);
    attn2_mfma<<<dim3(N_ / 64, H_, B_), 256, 0, stream>>>(qk_bf, qT_bf, lse, AqAk);
    // per row-chunk: hid = relu(g @ xi^T); x += alpha * [AqAk|hid] @ B2^T
    for (int r0 = 0; r0 < MN; r0 += R) {
      const int rows = (MN - r0) < R ? (MN - r0) : R;
      gemm128<true><<<(M_ / 128) * (rows / 128), 256, 0, stream>>>(
          g_bf + (size_t)r0 * D_, xi_bf, hid_bf, M_, D_, M_ / 128);
      gemm_update<<<(D_ / 64) * (rows / 128), 256, 0, stream>>>(
          AqAk + (size_t)r0 * 1536, hid_bf, B2_bf, x + (size_t)r0 * D_, ALPHA_);
    }
  }
}

// Round 7
// 3282.436 us; speedup vs baseline: 9.7218x; 1.0170x over previous
//
#include <hip/hip_runtime.h>
#include <math.h>

#define B_ 8
#define N_ 1024
#define D_ 768
#define H_ 12
#define Y_ 64
#define M_ 3072
#define STEPS_ 12
#define ALPHA_ 0.1f
#define BETA_ 0.125f
#define EPS_ 1e-5f

typedef __attribute__((ext_vector_type(8))) short bf16x8;
typedef __attribute__((ext_vector_type(8))) unsigned short u16x8;
typedef __attribute__((ext_vector_type(4))) float f32x4;

__device__ inline unsigned short f2bf(float f) {
  union { float f; unsigned int u; } v; v.f = f;
  unsigned int r = (v.u + 0x7fffu + ((v.u >> 16) & 1u)) >> 16;
  return (unsigned short)r;
}

__device__ inline void async_copy16(const void* g, void* l) {
  __builtin_amdgcn_global_load_lds(
      (const __attribute__((address_space(1))) unsigned int*)g,
      (__attribute__((address_space(3))) unsigned int*)l, 16, 0, 0);
}

// bijective XCD-aware remap of a 1D grid (m204 formula)
__device__ inline int xcd_remap(int bid, int nwg) {
  const int qd = nwg >> 3, rm = nwg & 7;
  const int xcd = bid & 7, idx = bid >> 3;
  return (xcd < rm ? xcd * (qd + 1) : rm * (qd + 1) + (xcd - rm) * qd) + idx;
}

// ---------------------------------------------------------------------------
// LayerNorm -> bf16 g
// ---------------------------------------------------------------------------
__global__ __launch_bounds__(256) void ln_kernel(const float* __restrict__ x,
    const float* __restrict__ gamma, const float* __restrict__ beta,
    unsigned short* __restrict__ g) {
  const int row = blockIdx.x;
  const int t = threadIdx.x;
  const float* xr = x + (size_t)row * D_;
  float v0 = xr[t], v1 = xr[t + 256], v2 = xr[t + 512];
  float s = v0 + v1 + v2;
  float sq = v0 * v0 + v1 * v1 + v2 * v2;
  #pragma unroll
  for (int off = 1; off < 64; off <<= 1) {
    s += __shfl_xor(s, off);
    sq += __shfl_xor(sq, off);
  }
  __shared__ float ss[4], ssq[4];
  const int wid = t >> 6;
  if ((t & 63) == 0) { ss[wid] = s; ssq[wid] = sq; }
  __syncthreads();
  s = ss[0] + ss[1] + ss[2] + ss[3];
  sq = ssq[0] + ssq[1] + ssq[2] + ssq[3];
  const float mu = s * (1.0f / D_);
  const float var = sq * (1.0f / D_) - mu * mu;
  const float r = rsqrtf(var + EPS_);
  unsigned short* gr = g + (size_t)row * D_;
  gr[t]       = f2bf(gamma[t]       * (v0 - mu) * r + beta[t]);
  gr[t + 256] = f2bf(gamma[t + 256] * (v1 - mu) * r + beta[t + 256]);
  gr[t + 512] = f2bf(gamma[t + 512] * (v2 - mu) * r + beta[t + 512]);
}

__global__ __launch_bounds__(256) void cvt_bf16(const float* __restrict__ in,
    unsigned short* __restrict__ out, int n) {
  int i = blockIdx.x * 256 + threadIdx.x;
  if (i < n) out[i] = f2bf(in[i]);
}

// transpose + convert: in[R][C] f32 -> out[c][koff + r] bf16 with row stride ldo
__global__ __launch_bounds__(256) void transpose_cvt(const float* __restrict__ in,
    unsigned short* __restrict__ out, int R, int C, int ldo, int koff) {
  __shared__ float tile[32][33];
  const int c0 = blockIdx.x * 32, r0 = blockIdx.y * 32;
  const int tx = threadIdx.x & 31, ty = threadIdx.x >> 5;
  #pragma unroll
  for (int i = 0; i < 32; i += 8)
    tile[ty + i][tx] = in[(size_t)(r0 + ty + i) * C + c0 + tx];
  __syncthreads();
  #pragma unroll
  for (int i = 0; i < 32; i += 8)
    out[(size_t)(c0 + ty + i) * ldo + koff + r0 + tx] = f2bf(tile[tx][ty + i]);
}

// ---------------------------------------------------------------------------
// bf16 MFMA GEMM 128x128, NT: C[*,N] = A[*,K] * B[N,K]^T, bf16 out (opt relu)
// WRT: additionally scatter transposed per-head copies into qT/kT [B,H,Y,N]
// (proj only: N=1536, rows are b*1024+n tokens). 1D grid (XCD-swizzled).
// ---------------------------------------------------------------------------
template <bool RELU, bool WRT>
__global__ __launch_bounds__(256) void gemm128(
    const unsigned short* __restrict__ A, const unsigned short* __restrict__ Bm,
    unsigned short* __restrict__ C, int N, int K, int gridN,
    unsigned short* __restrict__ qT, unsigned short* __restrict__ kT) {
  __shared__ __align__(16) unsigned short As[128 * 64];
  __shared__ __align__(16) unsigned short Bs[128 * 64];
  const int t = threadIdx.x;
  const int f = xcd_remap(blockIdx.x, gridDim.x);
  const int n0 = (f % gridN) * 128;
  const int m0 = (f / gridN) * 128;
  const int w = t >> 6;
  const int l = t & 63;
  const int wr = (w >> 1) * 64;
  const int wc = (w & 1) * 64;

  f32x4 acc[4][4];
  #pragma unroll
  for (int m = 0; m < 4; ++m)
    #pragma unroll
    for (int n = 0; n < 4; ++n) {
      f32x4 z = {0.f, 0.f, 0.f, 0.f};
      acc[m][n] = z;
    }

  for (int kt = 0; kt < K; kt += 64) {
    #pragma unroll
    for (int i = 0; i < 4; ++i) {
      const int flat = i * 4096 + t * 16;
      const int row = flat >> 7;
      const int slog = ((flat >> 4) & 7) ^ (row & 7);
      async_copy16(A + (size_t)(m0 + row) * K + kt + slog * 8, (char*)As + flat);
      async_copy16(Bm + (size_t)(n0 + row) * K + kt + slog * 8, (char*)Bs + flat);
    }
    __syncthreads();
    #pragma unroll
    for (int kk = 0; kk < 2; ++kk) {
      bf16x8 a[4], b[4];
      const int lr = l & 15;
      const int sl = kk * 4 + (l >> 4);
      #pragma unroll
      for (int m = 0; m < 4; ++m) {
        const int row = wr + m * 16 + lr;
        a[m] = *(const bf16x8*)((const char*)As + row * 128 + ((sl ^ (row & 7)) << 4));
      }
      #pragma unroll
      for (int n = 0; n < 4; ++n) {
        const int row = wc + n * 16 + lr;
        b[n] = *(const bf16x8*)((const char*)Bs + row * 128 + ((sl ^ (row & 7)) << 4));
      }
      #pragma unroll
      for (int m = 0; m < 4; ++m)
        #pragma unroll
        for (int n = 0; n < 4; ++n)
          acc[m][n] = __builtin_amdgcn_mfma_f32_16x16x32_bf16(a[m], b[n], acc[m][n], 0, 0, 0);
    }
    __syncthreads();
  }

  const int cr = (l >> 4) * 4;
  const int cc = l & 15;
  #pragma unroll
  for (int m = 0; m < 4; ++m)
    #pragma unroll
    for (int n = 0; n < 4; ++n) {
      const int col = n0 + wc + n * 16 + cc;
      unsigned long long pk = 0;
      #pragma unroll
      for (int j = 0; j < 4; ++j) {
        const int row = m0 + wr + m * 16 + cr + j;
        float v = acc[m][n][j];
        if (RELU) v = v > 0.f ? v : 0.f;
        const unsigned short bv = f2bf(v);
        C[(size_t)row * N + col] = bv;
        if (WRT) pk |= (unsigned long long)bv << (16 * j);
      }
      if (WRT) {
        const int row0 = m0 + wr + m * 16 + cr;       // 4-aligned token index
        const int bb = row0 >> 10, nn = row0 & 1023;
        const int hy = (col < 768) ? col : (col - 768);  // FIX: 768 not pow2
        unsigned short* T = (col < 768) ? qT : kT;
        *(unsigned long long*)(T + ((size_t)bb * 768 + hy) * N_ + nn) = pk;
      }
    }
}

// ---------------------------------------------------------------------------
// Fused update GEMM: x[m][n] += alpha * sum_k Acat[m][k] * B2[n][k]
// Acat = [AqAk (ld 1536) | hid (ld 3072)] split at k=1536; K=4608, N=768.
// BM=128, BN=64, 1D grid (XCD-swizzled), gridN = 12.
// ---------------------------------------------------------------------------
__global__ __launch_bounds__(256) void gemm_update(
    const unsigned short* __restrict__ A1,  // AqAk chunk base, ld 1536
    const unsigned short* __restrict__ A2,  // hid chunk base, ld 3072
    const unsigned short* __restrict__ B2,  // [768][4608]
    float* __restrict__ x,                  // chunk base, ld 768
    float alpha) {
  __shared__ __align__(16) unsigned short As[128 * 64];
  __shared__ __align__(16) unsigned short Bs[64 * 64];
  const int t = threadIdx.x;
  const int f = xcd_remap(blockIdx.x, gridDim.x);
  const int n0 = (f % 12) * 64;
  const int m0 = (f / 12) * 128;
  const int w = t >> 6;
  const int l = t & 63;
  const int wr = (w >> 1) * 64;
  const int wc = (w & 1) * 32;

  f32x4 acc[4][2];
  #pragma unroll
  for (int m = 0; m < 4; ++m)
    #pragma unroll
    for (int n = 0; n < 2; ++n) {
      f32x4 z = {0.f, 0.f, 0.f, 0.f};
      acc[m][n] = z;
    }

  for (int kt = 0; kt < 4608; kt += 64) {
    #pragma unroll
    for (int i = 0; i < 4; ++i) {
      const int flat = i * 4096 + t * 16;
      const int row = flat >> 7;
      const int slog = ((flat >> 4) & 7) ^ (row & 7);
      const unsigned short* src = (kt < 1536)
          ? A1 + (size_t)(m0 + row) * 1536 + kt + slog * 8
          : A2 + (size_t)(m0 + row) * 3072 + (kt - 1536) + slog * 8;
      async_copy16(src, (char*)As + flat);
    }
    #pragma unroll
    for (int i = 0; i < 2; ++i) {
      const int flat = i * 4096 + t * 16;
      const int row = flat >> 7;
      const int slog = ((flat >> 4) & 7) ^ (row & 7);
      async_copy16(B2 + (size_t)(n0 + row) * 4608 + kt + slog * 8, (char*)Bs + flat);
    }
    __syncthreads();
    #pragma unroll
    for (int kk = 0; kk < 2; ++kk) {
      bf16x8 a[4], b[2];
      const int lr = l & 15;
      const int sl = kk * 4 + (l >> 4);
      #pragma unroll
      for (int m = 0; m < 4; ++m) {
        const int row = wr + m * 16 + lr;
        a[m] = *(const bf16x8*)((const char*)As + row * 128 + ((sl ^ (row & 7)) << 4));
      }
      #pragma unroll
      for (int n = 0; n < 2; ++n) {
        const int row = wc + n * 16 + lr;
        b[n] = *(const bf16x8*)((const char*)Bs + row * 128 + ((sl ^ (row & 7)) << 4));
      }
      #pragma unroll
      for (int m = 0; m < 4; ++m)
        #pragma unroll
        for (int n = 0; n < 2; ++n)
          acc[m][n] = __builtin_amdgcn_mfma_f32_16x16x32_bf16(a[m], b[n], acc[m][n], 0, 0, 0);
    }
    __syncthreads();
  }

  const int cr = (l >> 4) * 4;
  const int cc = l & 15;
  #pragma unroll
  for (int m = 0; m < 4; ++m)
    #pragma unroll
    for (int n = 0; n < 2; ++n) {
      const int col = n0 + wc + n * 16 + cc;
      #pragma unroll
      for (int j = 0; j < 4; ++j) {
        const int row = m0 + wr + m * 16 + cr + j;
        float* cp = x + (size_t)row * 768 + col;
        *cp += alpha * acc[m][n][j];
      }
    }
}

// ---------------------------------------------------------------------------
// Attention pass 1 (MFMA flash), KVBLK=128. q/k strided in qk (ld 1536, k at
// +768); Aq out into AqAk (ld 1536, offset 0). lse f32 [B,H,N].
// ---------------------------------------------------------------------------
__global__ __launch_bounds__(256) void attn1_mfma(
    const unsigned short* __restrict__ qk, const unsigned short* __restrict__ kT,
    unsigned short* __restrict__ AqAk, float* __restrict__ lse) {
  __shared__ __align__(16) unsigned short Ks[128 * 64];
  __shared__ __align__(16) unsigned short KTs[64 * 128];
  __shared__ __align__(16) unsigned short Ps[4 * 16 * 128];
  const int n0 = blockIdx.x * 64;
  const int h = blockIdx.y;
  const int b = blockIdx.z;
  const int t = threadIdx.x;
  const int w = t >> 6;
  const int l = t & 63;
  const int g = l >> 4;
  const int ql = l & 15;
  char* psw = (char*)(Ps + w * 2048);
  const int LD = 1536;

  bf16x8 qf[2];
  {
    const unsigned short* qrow =
        qk + ((size_t)(b * N_ + n0 + w * 16 + ql)) * LD + h * Y_;
    qf[0] = *(const bf16x8*)(qrow + g * 8);
    qf[1] = *(const bf16x8*)(qrow + 32 + g * 8);
  }
  const unsigned short* kbase = qk + (size_t)b * N_ * LD + 768 + h * Y_;
  const unsigned short* kTbase = kT + ((size_t)(b * H_ + h)) * Y_ * N_;

  f32x4 acc[4];
  #pragma unroll
  for (int yf = 0; yf < 4; ++yf) { f32x4 z = {0.f,0.f,0.f,0.f}; acc[yf] = z; }
  float mmax = -1e30f, lsum = 0.f;

  for (int mc = 0; mc < N_; mc += 128) {
    // stage K tile [128 keys][64 y] and K^T tile [64 y][128 keys]
    #pragma unroll
    for (int i = 0; i < 4; ++i) {
      const int flat = i * 4096 + t * 16;
      const int row = flat >> 7;
      const int slog = ((flat >> 4) & 7) ^ (row & 7);
      async_copy16(kbase + (size_t)(mc + row) * LD + slog * 8, (char*)Ks + flat);
    }
    #pragma unroll
    for (int i = 0; i < 4; ++i) {
      const int flat = i * 4096 + t * 16;
      const int row = flat >> 8;
      const int slog = ((flat >> 4) & 15) ^ (row & 7);
      async_copy16(kTbase + (size_t)row * N_ + mc + slog * 8, (char*)KTs + flat);
    }
    __syncthreads();

    // S = K . Q^T  (rows = 128 keys, cols = wave's 16 queries)
    f32x4 s[8];
    __builtin_amdgcn_s_setprio(1);
    #pragma unroll
    for (int f = 0; f < 8; ++f) {
      f32x4 z = {0.f,0.f,0.f,0.f}; s[f] = z;
      #pragma unroll
      for (int ks = 0; ks < 2; ++ks) {
        const int key = f * 16 + ql;
        bf16x8 a = *(const bf16x8*)((const char*)Ks + key * 128 +
                                    (((ks * 4 + g) ^ (key & 7)) << 4));
        s[f] = __builtin_amdgcn_mfma_f32_16x16x32_bf16(a, qf[ks], s[f], 0, 0, 0);
      }
    }
    __builtin_amdgcn_s_setprio(0);
    // online softmax over 128 keys (32/lane + shfl over 4 lane groups)
    float rm = -1e30f;
    #pragma unroll
    for (int f = 0; f < 8; ++f)
      #pragma unroll
      for (int j = 0; j < 4; ++j) {
        const float v = s[f][j] * BETA_;
        s[f][j] = v;
        rm = fmaxf(rm, v);
      }
    rm = fmaxf(rm, __shfl_xor(rm, 16));
    rm = fmaxf(rm, __shfl_xor(rm, 32));
    const float nm = fmaxf(mmax, rm);
    const float sc = __expf(mmax - nm);
    float rs = 0.f;
    #pragma unroll
    for (int f = 0; f < 8; ++f) {
      unsigned short p4[4];
      #pragma unroll
      for (int j = 0; j < 4; ++j) {
        const float pvj = __expf(s[f][j] - nm);
        rs += pvj;
        p4[j] = f2bf(pvj);
      }
      unsigned long long pk = (unsigned long long)p4[0] |
          ((unsigned long long)p4[1] << 16) |
          ((unsigned long long)p4[2] << 32) |
          ((unsigned long long)p4[3] << 48);
      const int sl = (f * 4 + g) ^ ((ql & 7) << 1);
      *(unsigned long long*)(psw + ql * 256 + sl * 8) = pk;
    }
    rs += __shfl_xor(rs, 16);
    rs += __shfl_xor(rs, 32);
    lsum = lsum * sc + rs;
    mmax = nm;
    #pragma unroll
    for (int yf = 0; yf < 4; ++yf) acc[yf] *= sc;
    // PV: acc[query rows][y cols] += P * K^T
    __builtin_amdgcn_s_setprio(1);
    #pragma unroll
    for (int ks2 = 0; ks2 < 4; ++ks2) {
      const int sl2 = (ks2 * 8 + g * 2) ^ ((ql & 7) << 1);
      bf16x8 pa = *(const bf16x8*)(psw + ql * 256 + sl2 * 8);
      #pragma unroll
      for (int yf = 0; yf < 4; ++yf) {
        const int y = yf * 16 + ql;
        bf16x8 bk = *(const bf16x8*)((const char*)KTs + y * 256 +
                                     (((ks2 * 4 + g) ^ (y & 7)) << 4));
        acc[yf] = __builtin_amdgcn_mfma_f32_16x16x32_bf16(pa, bk, acc[yf], 0, 0, 0);
      }
    }
    __builtin_amdgcn_s_setprio(0);
    __syncthreads();
  }

  float linv[4];
  #pragma unroll
  for (int j = 0; j < 4; ++j)
    linv[j] = 1.0f / __shfl(lsum, (g << 4) + g * 4 + j);
  #pragma unroll
  for (int yf = 0; yf < 4; ++yf)
    #pragma unroll
    for (int j = 0; j < 4; ++j) {
      const int row = n0 + w * 16 + g * 4 + j;
      AqAk[((size_t)(b * N_ + row)) * LD + h * Y_ + yf * 16 + ql] =
          f2bf(acc[yf][j] * linv[j]);
    }
  if (g == 0)
    lse[((size_t)b * H_ + h) * N_ + n0 + w * 16 + ql] = mmax + __logf(lsum);
}

// ---------------------------------------------------------------------------
// Attention pass 2 (MFMA), NBLK=128. Ak out into AqAk (ld 1536, offset 768).
// ---------------------------------------------------------------------------
__global__ __launch_bounds__(256) void attn2_mfma(
    const unsigned short* __restrict__ qk, const unsigned short* __restrict__ qT,
    const float* __restrict__ lse, unsigned short* __restrict__ AqAk) {
  __shared__ __align__(16) unsigned short Qs[128 * 64];
  __shared__ __align__(16) unsigned short QTs[64 * 128];
  __shared__ __align__(16) unsigned short Ws[4 * 16 * 128];
  __shared__ float lse_s[128];
  const int m0 = blockIdx.x * 64;
  const int h = blockIdx.y;
  const int b = blockIdx.z;
  const int t = threadIdx.x;
  const int w = t >> 6;
  const int l = t & 63;
  const int g = l >> 4;
  const int ql = l & 15;
  char* wsw = (char*)(Ws + w * 2048);
  const int LD = 1536;

  bf16x8 ka[2];
  {
    const unsigned short* krow =
        qk + ((size_t)(b * N_ + m0 + w * 16 + ql)) * LD + 768 + h * Y_;
    ka[0] = *(const bf16x8*)(krow + g * 8);
    ka[1] = *(const bf16x8*)(krow + 32 + g * 8);
  }
  const unsigned short* qbase = qk + (size_t)b * N_ * LD + h * Y_;
  const unsigned short* qTbase = qT + ((size_t)(b * H_ + h)) * Y_ * N_;
  const float* lbase = lse + ((size_t)b * H_ + h) * N_;

  f32x4 acc[4];
  #pragma unroll
  for (int yf = 0; yf < 4; ++yf) { f32x4 z = {0.f,0.f,0.f,0.f}; acc[yf] = z; }

  for (int nc = 0; nc < N_; nc += 128) {
    #pragma unroll
    for (int i = 0; i < 4; ++i) {
      const int flat = i * 4096 + t * 16;
      const int row = flat >> 7;
      const int slog = ((flat >> 4) & 7) ^ (row & 7);
      async_copy16(qbase + (size_t)(nc + row) * LD + slog * 8, (char*)Qs + flat);
    }
    #pragma unroll
    for (int i = 0; i < 4; ++i) {
      const int flat = i * 4096 + t * 16;
      const int row = flat >> 8;
      const int slog = ((flat >> 4) & 15) ^ (row & 7);
      async_copy16(qTbase + (size_t)row * N_ + nc + slog * 8, (char*)QTs + flat);
    }
    if (t < 128) lse_s[t] = lbase[nc + t];
    __syncthreads();

    // S^T = Q . K^T (rows = 128 queries, cols = wave's 16 keys)
    f32x4 s[8];
    __builtin_amdgcn_s_setprio(1);
    #pragma unroll
    for (int f = 0; f < 8; ++f) {
      f32x4 z = {0.f,0.f,0.f,0.f}; s[f] = z;
      #pragma unroll
      for (int ks = 0; ks < 2; ++ks) {
        const int qr = f * 16 + ql;
        bf16x8 a = *(const bf16x8*)((const char*)Qs + qr * 128 +
                                    (((ks * 4 + g) ^ (qr & 7)) << 4));
        s[f] = __builtin_amdgcn_mfma_f32_16x16x32_bf16(a, ka[ks], s[f], 0, 0, 0);
      }
    }
    __builtin_amdgcn_s_setprio(0);
    // W = exp(beta*S - lse[query]) -> Ws[key][query]
    #pragma unroll
    for (int f = 0; f < 8; ++f) {
      unsigned short w4[4];
      #pragma unroll
      for (int j = 0; j < 4; ++j) {
        const float wv = __expf(s[f][j] * BETA_ - lse_s[f * 16 + g * 4 + j]);
        w4[j] = f2bf(wv);
      }
      unsigned long long pk =
          (unsigned long long)w4[0] | ((unsigned long long)w4[1] << 16) |
          ((unsigned long long)w4[2] << 32) | ((unsigned long long)w4[3] << 48);
      const int sl = (f * 4 + g) ^ ((ql & 7) << 1);
      *(unsigned long long*)(wsw + ql * 256 + sl * 8) = pk;
    }
    // PV: acc[key rows][y cols] += W * Q^T
    __builtin_amdgcn_s_setprio(1);
    #pragma unroll
    for (int ks2 = 0; ks2 < 4; ++ks2) {
      const int sl2 = (ks2 * 8 + g * 2) ^ ((ql & 7) << 1);
      bf16x8 wa = *(const bf16x8*)(wsw + ql * 256 + sl2 * 8);
      #pragma unroll
      for (int yf = 0; yf < 4; ++yf) {
        const int y = yf * 16 + ql;
        bf16x8 bq = *(const bf16x8*)((const char*)QTs + y * 256 +
                                     (((ks2 * 4 + g) ^ (y & 7)) << 4));
        acc[yf] = __builtin_amdgcn_mfma_f32_16x16x32_bf16(wa, bq, acc[yf], 0, 0, 0);
      }
    }
    __builtin_amdgcn_s_setprio(0);
    __syncthreads();
  }

  #pragma unroll
  for (int yf = 0; yf < 4; ++yf)
    #pragma unroll
    for (int j = 0; j < 4; ++j) {
      const int row = m0 + w * 16 + g * 4 + j;
      AqAk[((size_t)(b * N_ + row)) * LD + 768 + h * Y_ + yf * 16 + ql] =
          f2bf(acc[yf][j]);
    }
}

// ---------------------------------------------------------------------------
extern "C" void kernel_launch(void* const* d_in, const int* in_sizes, int n_in,
                              void* d_out, int out_size, void* d_ws, size_t ws_size,
                              hipStream_t stream) {
  const float* x0    = (const float*)d_in[0];
  const float* gamma = (const float*)d_in[1];
  const float* beta  = (const float*)d_in[2];
  const float* wq    = (const float*)d_in[3];
  const float* wk    = (const float*)d_in[4];
  const float* xi    = (const float*)d_in[5];
  float* x = (float*)d_out;

  const size_t SZ = (size_t)B_ * N_ * D_;   // 6291456
  char* wsp = (char*)d_ws;
  size_t off = 0;
  auto alloc = [&](size_t bytes) -> void* {
    off = (off + 255) & ~(size_t)255;
    void* p = wsp + off;
    off += bytes;
    return p;
  };
  unsigned short* g_bf   = (unsigned short*)alloc(SZ * 2);
  unsigned short* qk_bf  = (unsigned short*)alloc(SZ * 2 * 2);        // [8192][1536]
  unsigned short* AqAk   = (unsigned short*)alloc(SZ * 2 * 2);        // [8192][1536]
  unsigned short* qT_bf  = (unsigned short*)alloc(SZ * 2);
  unsigned short* kT_bf  = (unsigned short*)alloc(SZ * 2);
  float*          lse    = (float*)alloc((size_t)B_ * H_ * N_ * 4);
  unsigned short* wqk_bf = (unsigned short*)alloc((size_t)2 * D_ * D_ * 2);   // [1536][768]
  unsigned short* xi_bf  = (unsigned short*)alloc((size_t)M_ * D_ * 2);       // [3072][768]
  unsigned short* B2_bf  = (unsigned short*)alloc((size_t)D_ * (2 * D_ + M_) * 2); // [768][4608]
  off = (off + 255) & ~(size_t)255;
  unsigned short* hid_bf = (unsigned short*)(wsp + off);
  size_t avail = ws_size > off ? ws_size - off : 0;
  long rmax = (long)(avail / ((size_t)M_ * 2));
  int R = (int)((rmax / 128) * 128);
  if (R > B_ * N_) R = B_ * N_;
  if (R < 128) R = 128;

  const int WQN = D_ * D_;
  const int XIN = M_ * D_;
  // B1 for proj: [wq; wk] rows
  cvt_bf16<<<(WQN + 255) / 256, 256, 0, stream>>>(wq, wqk_bf, WQN);
  cvt_bf16<<<(WQN + 255) / 256, 256, 0, stream>>>(wk, wqk_bf + (size_t)D_ * D_, WQN);
  cvt_bf16<<<(XIN + 255) / 256, 256, 0, stream>>>(xi, xi_bf, XIN);
  // B2 = [wqT | wkT | xiT] along k, ld 4608
  const int LDB2 = 2 * D_ + M_;  // 4608
  transpose_cvt<<<dim3(D_ / 32, D_ / 32), 256, 0, stream>>>(wq, B2_bf, D_, D_, LDB2, 0);
  transpose_cvt<<<dim3(D_ / 32, D_ / 32), 256, 0, stream>>>(wk, B2_bf, D_, D_, LDB2, D_);
  transpose_cvt<<<dim3(D_ / 32, M_ / 32), 256, 0, stream>>>(xi, B2_bf, M_, D_, LDB2, 2 * D_);

  hipMemcpyAsync(x, x0, SZ * sizeof(float), hipMemcpyDeviceToDevice, stream);

  const int MN = B_ * N_;  // 8192
  for (int step = 0; step < STEPS_; ++step) {
    ln_kernel<<<MN, 256, 0, stream>>>(x, gamma, beta, g_bf);
    // qk = g @ [Wq;Wk]^T -> [8192][1536] bf16, with fused qT/kT scatter
    gemm128<false, true><<<(1536 / 128) * (MN / 128), 256, 0, stream>>>(
        g_bf, wqk_bf, qk_bf, 1536, D_, 1536 / 128, qT_bf, kT_bf);
    // attention gradient pieces -> AqAk
    attn1_mfma<<<dim3(N_ / 64, H_, B_), 256, 0, stream>>>(qk_bf, kT_bf, AqAk, lse);
    attn2_mfma<<<dim3(N_ / 64, H_, B_), 256, 0, stream>>>(qk_bf, qT_bf, lse, AqAk);
    // per row-chunk: hid = relu(g @ xi^T); x += alpha * [AqAk|hid] @ B2^T
    for (int r0 = 0; r0 < MN; r0 += R) {
      const int rows = (MN - r0) < R ? (MN - r0) : R;
      gemm128<true, false><<<(M_ / 128) * (rows / 128), 256, 0, stream>>>(
          g_bf + (size_t)r0 * D_, xi_bf, hid_bf, M_, D_, M_ / 128, nullptr, nullptr);
      gemm_update<<<(D_ / 64) * (rows / 128), 256, 0, stream>>>(
          AqAk + (size_t)r0 * 1536, hid_bf, B2_bf, x + (size_t)r0 * D_, ALPHA_);
    }
  }
}